// Round 1
// baseline (1530.731 us; speedup 1.0000x reference)
//
#include <hip/hip_runtime.h>
#include <math.h>

#define BATCH 2
#define SEQ   2048
#define DIM   1024
#define NST   16
#define DTR   64

__device__ __forceinline__ float softplus_f(float v) {
  // logaddexp(v, 0) stable form — matches jax.nn.softplus
  return fmaxf(v, 0.f) + log1pf(expf(-fabsf(v)));
}
__device__ __forceinline__ float silu_f(float v) {
  return v / (1.f + expf(-v));
}

#define FMA_ROW(i, av)                                        \
  acc[i][0] = fmaf(av, b.x, acc[i][0]);                       \
  acc[i][1] = fmaf(av, b.y, acc[i][1]);                       \
  acc[i][2] = fmaf(av, b.z, acc[i][2]);                       \
  acc[i][3] = fmaf(av, b.w, acc[i][3]);

// ---------------- K1: in_proj GEMM ----------------
// C[c, n] = sum_k w[c,k] * x[n,k],  c in [0,2048), n = b*SEQ + t in [0,4096)
// c < DIM  -> xcraw (b, c, t) channel-major
// c >= DIM -> z     (n, c-DIM) row-major
__global__ __launch_bounds__(256) void k1_inproj(
    const float* __restrict__ x, const float* __restrict__ w,
    float* __restrict__ xcraw, float* __restrict__ z) {
  __shared__ float As[16][68];
  __shared__ float Bs[16][68];
  const int tid = threadIdx.x;
  const int n0 = blockIdx.x * 64;
  const int c0 = blockIdx.y * 64;
  const int tx = tid & 15, ty = tid >> 4;
  const int lrow = tid >> 2, lcol = (tid & 3) * 4;
  const float* wp = w + (size_t)(c0 + lrow) * DIM + lcol;
  const float* xp = x + (size_t)(n0 + lrow) * DIM + lcol;
  float acc[4][4] = {{0.f}};
  for (int k = 0; k < DIM; k += 16) {
    const float4 av = *(const float4*)(wp + k);
    const float4 bv = *(const float4*)(xp + k);
    __syncthreads();
    As[lcol + 0][lrow] = av.x; As[lcol + 1][lrow] = av.y;
    As[lcol + 2][lrow] = av.z; As[lcol + 3][lrow] = av.w;
    Bs[lcol + 0][lrow] = bv.x; Bs[lcol + 1][lrow] = bv.y;
    Bs[lcol + 2][lrow] = bv.z; Bs[lcol + 3][lrow] = bv.w;
    __syncthreads();
#pragma unroll
    for (int kk = 0; kk < 16; ++kk) {
      const float4 a = *(const float4*)&As[kk][ty * 4];
      const float4 b = *(const float4*)&Bs[kk][tx * 4];
      FMA_ROW(0, a.x) FMA_ROW(1, a.y) FMA_ROW(2, a.z) FMA_ROW(3, a.w)
    }
  }
  const int c = c0 + ty * 4;
  const int n = n0 + tx * 4;
  const int b = n >> 11;
  const int t = n & (SEQ - 1);
  if (c < DIM) {
#pragma unroll
    for (int i = 0; i < 4; ++i) {
      *(float4*)(xcraw + ((size_t)b * DIM + (c + i)) * SEQ + t) =
          make_float4(acc[i][0], acc[i][1], acc[i][2], acc[i][3]);
    }
  } else {
    const int cz = c - DIM;
#pragma unroll
    for (int j = 0; j < 4; ++j) {
      *(float4*)(z + (size_t)(n + j) * DIM + cz) =
          make_float4(acc[0][j], acc[1][j], acc[2][j], acc[3][j]);
    }
  }
}

// ---------------- conv: depthwise k=3, pad=1, along t ----------------
__global__ __launch_bounds__(256) void k_conv(
    const float* __restrict__ xcraw, const float* __restrict__ cw,
    const float* __restrict__ cb, float* __restrict__ xc) {
  const int idx = blockIdx.x * 256 + threadIdx.x;  // < B*DIM*SEQ/4
  const int t0 = (idx & (SEQ / 4 - 1)) * 4;
  const int r = idx >> 9;  // b*DIM + d
  const int d = r & (DIM - 1);
  const float w0 = cw[d * 3 + 0], w1 = cw[d * 3 + 1], w2 = cw[d * 3 + 2];
  const float bias = cb[d];
  const float* in = xcraw + (size_t)r * SEQ;
  float o[4];
#pragma unroll
  for (int j = 0; j < 4; ++j) {
    const int t = t0 + j;
    const float xm = (t > 0) ? in[t - 1] : 0.f;
    const float x0 = in[t];
    const float xp = (t < SEQ - 1) ? in[t + 1] : 0.f;
    o[j] = fmaf(w0, xm, fmaf(w1, x0, fmaf(w2, xp, bias)));
  }
  *(float4*)(xc + (size_t)r * SEQ + t0) = make_float4(o[0], o[1], o[2], o[3]);
}

// ---------------- K2: x_proj GEMM ----------------
// xdbl[b, j, t] = sum_d wp[j,d] * xc[b,d,t],  j < 96
__global__ __launch_bounds__(256) void k2_xproj(
    const float* __restrict__ xc, const float* __restrict__ wp,
    float* __restrict__ xdbl) {
  __shared__ float As[16][96];  // As[kk][j]
  __shared__ float Bs[16][68];  // Bs[kk][tt]
  const int tid = threadIdx.x;
  const int b = blockIdx.y;
  const int t0 = blockIdx.x * 64;
  const int tx = tid & 15, ty = tid >> 4;  // ty 0..15
  const int bk = tid >> 4, bt4 = (tid & 15) * 4;
  float acc[6][4] = {{0.f}};
  for (int k = 0; k < DIM; k += 16) {
    float a_reg[6];
#pragma unroll
    for (int i = 0; i < 6; ++i) {
      const int ii = tid + 256 * i;
      a_reg[i] = wp[(size_t)(ii >> 4) * DIM + k + (ii & 15)];
    }
    const float4 bv =
        *(const float4*)(xc + ((size_t)b * DIM + k + bk) * SEQ + t0 + bt4);
    __syncthreads();
#pragma unroll
    for (int i = 0; i < 6; ++i) {
      const int ii = tid + 256 * i;
      As[ii & 15][ii >> 4] = a_reg[i];
    }
    Bs[bk][bt4 + 0] = bv.x; Bs[bk][bt4 + 1] = bv.y;
    Bs[bk][bt4 + 2] = bv.z; Bs[bk][bt4 + 3] = bv.w;
    __syncthreads();
#pragma unroll
    for (int kk = 0; kk < 16; ++kk) {
      const float4 b4 = *(const float4*)&Bs[kk][tx * 4];
#pragma unroll
      for (int i = 0; i < 6; ++i) {
        const float a = As[kk][ty + 16 * i];
        acc[i][0] = fmaf(a, b4.x, acc[i][0]);
        acc[i][1] = fmaf(a, b4.y, acc[i][1]);
        acc[i][2] = fmaf(a, b4.z, acc[i][2]);
        acc[i][3] = fmaf(a, b4.w, acc[i][3]);
      }
    }
  }
#pragma unroll
  for (int i = 0; i < 6; ++i) {
    const int j = ty + 16 * i;
    *(float4*)(xdbl + ((size_t)b * 96 + j) * SEQ + t0 + tx * 4) =
        make_float4(acc[i][0], acc[i][1], acc[i][2], acc[i][3]);
  }
}

// ---------------- K3: dt_proj GEMM + softplus ----------------
// delta[b,d,t] = softplus( sum_r dtw[d,r]*xdbl[b,r,t] + dtb[d] )
__global__ __launch_bounds__(256) void k3_dtproj(
    const float* __restrict__ xdbl, const float* __restrict__ dtw,
    const float* __restrict__ dtb, float* __restrict__ delta) {
  __shared__ float As[16][68];
  __shared__ float Bs[16][68];
  const int tid = threadIdx.x;
  const int b = blockIdx.z;
  const int d0 = blockIdx.y * 64;
  const int t0 = blockIdx.x * 64;
  const int tx = tid & 15, ty = tid >> 4;
  const int lrow = tid >> 2, lcol = (tid & 3) * 4;
  const int bk = tid >> 4, bt4 = (tid & 15) * 4;
  float acc[4][4] = {{0.f}};
  for (int k = 0; k < DTR; k += 16) {
    const float4 av =
        *(const float4*)(dtw + (size_t)(d0 + lrow) * DTR + k + lcol);
    const float4 bv =
        *(const float4*)(xdbl + ((size_t)b * 96 + k + bk) * SEQ + t0 + bt4);
    __syncthreads();
    As[lcol + 0][lrow] = av.x; As[lcol + 1][lrow] = av.y;
    As[lcol + 2][lrow] = av.z; As[lcol + 3][lrow] = av.w;
    Bs[bk][bt4 + 0] = bv.x; Bs[bk][bt4 + 1] = bv.y;
    Bs[bk][bt4 + 2] = bv.z; Bs[bk][bt4 + 3] = bv.w;
    __syncthreads();
#pragma unroll
    for (int kk = 0; kk < 16; ++kk) {
      const float4 a = *(const float4*)&As[kk][ty * 4];
      const float4 b = *(const float4*)&Bs[kk][tx * 4];
      FMA_ROW(0, a.x) FMA_ROW(1, a.y) FMA_ROW(2, a.z) FMA_ROW(3, a.w)
    }
  }
#pragma unroll
  for (int i = 0; i < 4; ++i) {
    const int d = d0 + ty * 4 + i;
    const float bias = dtb[d];
    float4 v;
    v.x = softplus_f(acc[i][0] + bias);
    v.y = softplus_f(acc[i][1] + bias);
    v.z = softplus_f(acc[i][2] + bias);
    v.w = softplus_f(acc[i][3] + bias);
    *(float4*)(delta + ((size_t)b * DIM + d) * SEQ + t0 + tx * 4) = v;
  }
}

// ---------------- scan: lane per (b,d,n), fused +u*D and y*silu(z) ----------------
__global__ __launch_bounds__(64) void k_scan(
    const float* __restrict__ delta, const float* __restrict__ u,
    const float* __restrict__ xdbl, const float* __restrict__ A_log,
    const float* __restrict__ Dp, const float* __restrict__ z,
    float* __restrict__ g) {
  const int lane = threadIdx.x;
  const int grp = lane >> 4, n = lane & 15;
  const int idx = blockIdx.x * 4 + grp;  // b*DIM + d
  const int b = idx >> 10, d = idx & (DIM - 1);
  const float A = -expf(A_log[d * NST + n]);
  const float Dprm = Dp[d];
  const float* drow = delta + (size_t)idx * SEQ;
  const float* urow = u + (size_t)idx * SEQ;
  const float* Brow = xdbl + ((size_t)b * 96 + DTR + n) * SEQ;
  const float* Crow = xdbl + ((size_t)b * 96 + DTR + NST + n) * SEQ;
  const float* zrow = z + (size_t)b * SEQ * DIM + d;
  float* grow = g + (size_t)b * SEQ * DIM + d;
  float s = 0.f;
  for (int t0 = 0; t0 < SEQ; t0 += 4) {
    const float4 dl = *(const float4*)(drow + t0);
    const float4 uu = *(const float4*)(urow + t0);
    const float4 Bv = *(const float4*)(Brow + t0);
    const float4 Cv = *(const float4*)(Crow + t0);
    const float dls[4] = {dl.x, dl.y, dl.z, dl.w};
    const float us[4] = {uu.x, uu.y, uu.z, uu.w};
    const float Bb[4] = {Bv.x, Bv.y, Bv.z, Bv.w};
    const float Cc[4] = {Cv.x, Cv.y, Cv.z, Cv.w};
#pragma unroll
    for (int j = 0; j < 4; ++j) {
      const float dA = __expf(dls[j] * A);
      const float dBu = dls[j] * us[j] * Bb[j];
      s = fmaf(dA, s, dBu);
      float yc = s * Cc[j];
      yc += __shfl_xor(yc, 1, 64);
      yc += __shfl_xor(yc, 2, 64);
      yc += __shfl_xor(yc, 4, 64);
      yc += __shfl_xor(yc, 8, 64);
      if (n == 0) {
        const int t = t0 + j;
        const float zz = zrow[(size_t)t * DIM];
        grow[(size_t)t * DIM] = fmaf(us[j], Dprm, yc) * silu_f(zz);
      }
    }
  }
}

// ---------------- K4: out_proj GEMM ----------------
// out[n, m] = sum_d g[n,d] * wo[m,d]
__global__ __launch_bounds__(256) void k4_outproj(
    const float* __restrict__ g, const float* __restrict__ wo,
    float* __restrict__ out) {
  __shared__ float As[16][68];
  __shared__ float Bs[16][68];
  const int tid = threadIdx.x;
  const int m0 = blockIdx.x * 64;
  const int n0 = blockIdx.y * 64;
  const int tx = tid & 15, ty = tid >> 4;
  const int lrow = tid >> 2, lcol = (tid & 3) * 4;
  const float* gp = g + (size_t)(n0 + lrow) * DIM + lcol;
  const float* wp = wo + (size_t)(m0 + lrow) * DIM + lcol;
  float acc[4][4] = {{0.f}};
  for (int k = 0; k < DIM; k += 16) {
    const float4 av = *(const float4*)(gp + k);
    const float4 bv = *(const float4*)(wp + k);
    __syncthreads();
    As[lcol + 0][lrow] = av.x; As[lcol + 1][lrow] = av.y;
    As[lcol + 2][lrow] = av.z; As[lcol + 3][lrow] = av.w;
    Bs[lcol + 0][lrow] = bv.x; Bs[lcol + 1][lrow] = bv.y;
    Bs[lcol + 2][lrow] = bv.z; Bs[lcol + 3][lrow] = bv.w;
    __syncthreads();
#pragma unroll
    for (int kk = 0; kk < 16; ++kk) {
      const float4 a = *(const float4*)&As[kk][ty * 4];
      const float4 b = *(const float4*)&Bs[kk][tx * 4];
      FMA_ROW(0, a.x) FMA_ROW(1, a.y) FMA_ROW(2, a.z) FMA_ROW(3, a.w)
    }
  }
#pragma unroll
  for (int i = 0; i < 4; ++i) {
    *(float4*)(out + (size_t)(n0 + ty * 4 + i) * DIM + m0 + tx * 4) =
        make_float4(acc[i][0], acc[i][1], acc[i][2], acc[i][3]);
  }
}

extern "C" void kernel_launch(void* const* d_in, const int* in_sizes, int n_in,
                              void* d_out, int out_size, void* d_ws,
                              size_t ws_size, hipStream_t stream) {
  const float* x          = (const float*)d_in[0];
  const float* in_proj_w  = (const float*)d_in[1];
  const float* conv_w     = (const float*)d_in[2];
  const float* conv_b     = (const float*)d_in[3];
  const float* A_log      = (const float*)d_in[4];
  const float* D_param    = (const float*)d_in[5];
  const float* x_proj_w   = (const float*)d_in[6];
  const float* dt_proj_w  = (const float*)d_in[7];
  const float* dt_proj_b  = (const float*)d_in[8];
  const float* out_proj_w = (const float*)d_in[9];
  float* out = (float*)d_out;
  float* ws = (float*)d_ws;

  const size_t PLANE = (size_t)BATCH * SEQ * DIM;  // 4M floats
  float* xcraw = ws;              // (b,d,t); dead after conv
  float* delta = ws;              // reuses xcraw region, (b,d,t)
  float* xc    = ws + PLANE;      // (b,d,t) post-conv
  float* zbuf  = ws + 2 * PLANE;  // (n,d)
  float* gbuf  = ws + 3 * PLANE;  // (n,d) gated scan output
  float* xdbl  = ws + 4 * PLANE;  // (b,96,t)

  k1_inproj<<<dim3(64, 32), 256, 0, stream>>>(x, in_proj_w, xcraw, zbuf);
  k_conv<<<dim3((BATCH * DIM * SEQ / 4) / 256), 256, 0, stream>>>(
      xcraw, conv_w, conv_b, xc);
  k2_xproj<<<dim3(SEQ / 64, BATCH), 256, 0, stream>>>(xc, x_proj_w, xdbl);
  k3_dtproj<<<dim3(SEQ / 64, DIM / 64, BATCH), 256, 0, stream>>>(
      xdbl, dt_proj_w, dt_proj_b, delta);
  k_scan<<<dim3(BATCH * DIM / 4), 64, 0, stream>>>(delta, xc, xdbl, A_log,
                                                   D_param, zbuf, gbuf);
  k4_outproj<<<dim3(DIM / 64, BATCH * SEQ / 64), 256, 0, stream>>>(
      gbuf, out_proj_w, out);
}

// Round 2
// 743.749 us; speedup vs baseline: 2.0581x; 2.0581x over previous
//
#include <hip/hip_runtime.h>
#include <math.h>

#define BATCH 2
#define SEQ   2048
#define DIM   1024
#define NST   16
#define DTR   64
#define NCH   16                    // time chunks for the scan
#define CHUNK (SEQ / NCH)           // 128 steps per chunk
#define LANES (BATCH * DIM * NST)   // 32768 scan lanes

__device__ __forceinline__ float softplus_f(float v) {
  return fmaxf(v, 0.f) + log1pf(expf(-fabsf(v)));
}
__device__ __forceinline__ float silu_f(float v) {
  return v / (1.f + expf(-v));
}

#define FMA_ROW(i, av)                                        \
  acc[i][0] = fmaf(av, b.x, acc[i][0]);                       \
  acc[i][1] = fmaf(av, b.y, acc[i][1]);                       \
  acc[i][2] = fmaf(av, b.z, acc[i][2]);                       \
  acc[i][3] = fmaf(av, b.w, acc[i][3]);

// ---------------- K1: in_proj GEMM ----------------
__global__ __launch_bounds__(256) void k1_inproj(
    const float* __restrict__ x, const float* __restrict__ w,
    float* __restrict__ xcraw, float* __restrict__ z) {
  __shared__ float As[16][68];
  __shared__ float Bs[16][68];
  const int tid = threadIdx.x;
  const int n0 = blockIdx.x * 64;
  const int c0 = blockIdx.y * 64;
  const int tx = tid & 15, ty = tid >> 4;
  const int lrow = tid >> 2, lcol = (tid & 3) * 4;
  const float* wp = w + (size_t)(c0 + lrow) * DIM + lcol;
  const float* xp = x + (size_t)(n0 + lrow) * DIM + lcol;
  float acc[4][4] = {{0.f}};
  for (int k = 0; k < DIM; k += 16) {
    const float4 av = *(const float4*)(wp + k);
    const float4 bv = *(const float4*)(xp + k);
    __syncthreads();
    As[lcol + 0][lrow] = av.x; As[lcol + 1][lrow] = av.y;
    As[lcol + 2][lrow] = av.z; As[lcol + 3][lrow] = av.w;
    Bs[lcol + 0][lrow] = bv.x; Bs[lcol + 1][lrow] = bv.y;
    Bs[lcol + 2][lrow] = bv.z; Bs[lcol + 3][lrow] = bv.w;
    __syncthreads();
#pragma unroll
    for (int kk = 0; kk < 16; ++kk) {
      const float4 a = *(const float4*)&As[kk][ty * 4];
      const float4 b = *(const float4*)&Bs[kk][tx * 4];
      FMA_ROW(0, a.x) FMA_ROW(1, a.y) FMA_ROW(2, a.z) FMA_ROW(3, a.w)
    }
  }
  const int c = c0 + ty * 4;
  const int n = n0 + tx * 4;
  const int b = n >> 11;
  const int t = n & (SEQ - 1);
  if (c < DIM) {
#pragma unroll
    for (int i = 0; i < 4; ++i) {
      *(float4*)(xcraw + ((size_t)b * DIM + (c + i)) * SEQ + t) =
          make_float4(acc[i][0], acc[i][1], acc[i][2], acc[i][3]);
    }
  } else {
    const int cz = c - DIM;
#pragma unroll
    for (int j = 0; j < 4; ++j) {
      *(float4*)(z + (size_t)(n + j) * DIM + cz) =
          make_float4(acc[0][j], acc[1][j], acc[2][j], acc[3][j]);
    }
  }
}

// ---------------- conv: depthwise k=3, pad=1, along t ----------------
__global__ __launch_bounds__(256) void k_conv(
    const float* __restrict__ xcraw, const float* __restrict__ cw,
    const float* __restrict__ cb, float* __restrict__ xc) {
  const int idx = blockIdx.x * 256 + threadIdx.x;
  const int t0 = (idx & (SEQ / 4 - 1)) * 4;
  const int r = idx >> 9;  // b*DIM + d
  const int d = r & (DIM - 1);
  const float w0 = cw[d * 3 + 0], w1 = cw[d * 3 + 1], w2 = cw[d * 3 + 2];
  const float bias = cb[d];
  const float* in = xcraw + (size_t)r * SEQ;
  float o[4];
#pragma unroll
  for (int j = 0; j < 4; ++j) {
    const int t = t0 + j;
    const float xm = (t > 0) ? in[t - 1] : 0.f;
    const float x0 = in[t];
    const float xp = (t < SEQ - 1) ? in[t + 1] : 0.f;
    o[j] = fmaf(w0, xm, fmaf(w1, x0, fmaf(w2, xp, bias)));
  }
  *(float4*)(xc + (size_t)r * SEQ + t0) = make_float4(o[0], o[1], o[2], o[3]);
}

// ---------------- K2: x_proj GEMM ----------------
__global__ __launch_bounds__(256) void k2_xproj(
    const float* __restrict__ xc, const float* __restrict__ wp,
    float* __restrict__ xdbl) {
  __shared__ float As[16][96];
  __shared__ float Bs[16][68];
  const int tid = threadIdx.x;
  const int b = blockIdx.y;
  const int t0 = blockIdx.x * 64;
  const int tx = tid & 15, ty = tid >> 4;
  const int bk = tid >> 4, bt4 = (tid & 15) * 4;
  float acc[6][4] = {{0.f}};
  for (int k = 0; k < DIM; k += 16) {
    float a_reg[6];
#pragma unroll
    for (int i = 0; i < 6; ++i) {
      const int ii = tid + 256 * i;
      a_reg[i] = wp[(size_t)(ii >> 4) * DIM + k + (ii & 15)];
    }
    const float4 bv =
        *(const float4*)(xc + ((size_t)b * DIM + k + bk) * SEQ + t0 + bt4);
    __syncthreads();
#pragma unroll
    for (int i = 0; i < 6; ++i) {
      const int ii = tid + 256 * i;
      As[ii & 15][ii >> 4] = a_reg[i];
    }
    Bs[bk][bt4 + 0] = bv.x; Bs[bk][bt4 + 1] = bv.y;
    Bs[bk][bt4 + 2] = bv.z; Bs[bk][bt4 + 3] = bv.w;
    __syncthreads();
#pragma unroll
    for (int kk = 0; kk < 16; ++kk) {
      const float4 b4 = *(const float4*)&Bs[kk][tx * 4];
#pragma unroll
      for (int i = 0; i < 6; ++i) {
        const float a = As[kk][ty + 16 * i];
        acc[i][0] = fmaf(a, b4.x, acc[i][0]);
        acc[i][1] = fmaf(a, b4.y, acc[i][1]);
        acc[i][2] = fmaf(a, b4.z, acc[i][2]);
        acc[i][3] = fmaf(a, b4.w, acc[i][3]);
      }
    }
  }
#pragma unroll
  for (int i = 0; i < 6; ++i) {
    const int j = ty + 16 * i;
    *(float4*)(xdbl + ((size_t)b * 96 + j) * SEQ + t0 + tx * 4) =
        make_float4(acc[i][0], acc[i][1], acc[i][2], acc[i][3]);
  }
}

// ---------------- K3: dt_proj GEMM + softplus ----------------
__global__ __launch_bounds__(256) void k3_dtproj(
    const float* __restrict__ xdbl, const float* __restrict__ dtw,
    const float* __restrict__ dtb, float* __restrict__ delta) {
  __shared__ float As[16][68];
  __shared__ float Bs[16][68];
  const int tid = threadIdx.x;
  const int b = blockIdx.z;
  const int d0 = blockIdx.y * 64;
  const int t0 = blockIdx.x * 64;
  const int tx = tid & 15, ty = tid >> 4;
  const int lrow = tid >> 2, lcol = (tid & 3) * 4;
  const int bk = tid >> 4, bt4 = (tid & 15) * 4;
  float acc[4][4] = {{0.f}};
  for (int k = 0; k < DTR; k += 16) {
    const float4 av =
        *(const float4*)(dtw + (size_t)(d0 + lrow) * DTR + k + lcol);
    const float4 bv =
        *(const float4*)(xdbl + ((size_t)b * 96 + k + bk) * SEQ + t0 + bt4);
    __syncthreads();
    As[lcol + 0][lrow] = av.x; As[lcol + 1][lrow] = av.y;
    As[lcol + 2][lrow] = av.z; As[lcol + 3][lrow] = av.w;
    Bs[bk][bt4 + 0] = bv.x; Bs[bk][bt4 + 1] = bv.y;
    Bs[bk][bt4 + 2] = bv.z; Bs[bk][bt4 + 3] = bv.w;
    __syncthreads();
#pragma unroll
    for (int kk = 0; kk < 16; ++kk) {
      const float4 a = *(const float4*)&As[kk][ty * 4];
      const float4 b = *(const float4*)&Bs[kk][tx * 4];
      FMA_ROW(0, a.x) FMA_ROW(1, a.y) FMA_ROW(2, a.z) FMA_ROW(3, a.w)
    }
  }
#pragma unroll
  for (int i = 0; i < 4; ++i) {
    const int d = d0 + ty * 4 + i;
    const float bias = dtb[d];
    float4 v;
    v.x = softplus_f(acc[i][0] + bias);
    v.y = softplus_f(acc[i][1] + bias);
    v.z = softplus_f(acc[i][2] + bias);
    v.w = softplus_f(acc[i][3] + bias);
    *(float4*)(delta + ((size_t)b * DIM + d) * SEQ + t0 + tx * 4) = v;
  }
}

// ---------------- scan pass 1: per-chunk product + local end state ----------------
// lane = (bd-group, n); block covers 4 bd; grid = 512 * NCH
__global__ __launch_bounds__(64) void k_scan_pass1(
    const float* __restrict__ delta, const float* __restrict__ u,
    const float* __restrict__ xdbl, const float* __restrict__ A_log,
    float* __restrict__ Pbuf, float* __restrict__ Sbuf) {
  const int lane = threadIdx.x;
  const int grp = lane >> 4, n = lane & 15;
  const int bdblk = blockIdx.x & 511;
  const int chunk = blockIdx.x >> 9;
  const int idx = bdblk * 4 + grp;  // b*DIM + d
  const int b = idx >> 10, d = idx & (DIM - 1);
  const float A = -expf(A_log[d * NST + n]);
  const int tc = chunk * CHUNK;
  const float* drow = delta + (size_t)idx * SEQ + tc;
  const float* urow = u + (size_t)idx * SEQ + tc;
  const float* Brow = xdbl + ((size_t)b * 96 + DTR + n) * SEQ + tc;
  float s = 0.f, dsum = 0.f;
  for (int t0 = 0; t0 < CHUNK; t0 += 4) {
    const float4 dl = *(const float4*)(drow + t0);
    const float4 uu = *(const float4*)(urow + t0);
    const float4 Bv = *(const float4*)(Brow + t0);
    const float dls[4] = {dl.x, dl.y, dl.z, dl.w};
    const float us[4] = {uu.x, uu.y, uu.z, uu.w};
    const float Bb[4] = {Bv.x, Bv.y, Bv.z, Bv.w};
#pragma unroll
    for (int j = 0; j < 4; ++j) {
      dsum += dls[j];
      const float dA = __expf(dls[j] * A);
      s = fmaf(dA, s, dls[j] * us[j] * Bb[j]);
    }
  }
  const int gi = chunk * LANES + bdblk * 64 + lane;
  Pbuf[gi] = __expf(dsum * A);   // prod of dA over the chunk
  Sbuf[gi] = s;                  // local end state (zero init)
}

// ---------------- scan mid: combine chunk summaries, emit entry states ----------------
// Sbuf is overwritten in place with the ENTRY state of each chunk.
__global__ __launch_bounds__(64) void k_scan_mid(
    const float* __restrict__ Pbuf, float* __restrict__ Sbuf) {
  const int gl = blockIdx.x * 64 + threadIdx.x;  // < LANES
  float run = 0.f;
#pragma unroll
  for (int c = 0; c < NCH; ++c) {
    const float p = Pbuf[c * LANES + gl];
    const float s = Sbuf[c * LANES + gl];
    Sbuf[c * LANES + gl] = run;
    run = fmaf(p, run, s);
  }
}

// ---------------- scan pass 2: seeded local scan + y reduce + gate ----------------
__global__ __launch_bounds__(64) void k_scan_pass2(
    const float* __restrict__ delta, const float* __restrict__ u,
    const float* __restrict__ xdbl, const float* __restrict__ A_log,
    const float* __restrict__ Dp, const float* __restrict__ z,
    const float* __restrict__ sInit, float* __restrict__ g) {
  const int lane = threadIdx.x;
  const int grp = lane >> 4, n = lane & 15;
  const int bdblk = blockIdx.x & 511;
  const int chunk = blockIdx.x >> 9;
  const int idx = bdblk * 4 + grp;  // b*DIM + d
  const int b = idx >> 10, d = idx & (DIM - 1);
  const float A = -expf(A_log[d * NST + n]);
  const float Dprm = Dp[d];
  const int tc = chunk * CHUNK;
  const float* drow = delta + (size_t)idx * SEQ + tc;
  const float* urow = u + (size_t)idx * SEQ + tc;
  const float* Brow = xdbl + ((size_t)b * 96 + DTR + n) * SEQ + tc;
  const float* Crow = xdbl + ((size_t)b * 96 + DTR + NST + n) * SEQ + tc;
  const float* zrow = z + ((size_t)b * SEQ + tc) * DIM + d;
  float* grow = g + ((size_t)b * SEQ + tc) * DIM + d;
  float s = sInit[chunk * LANES + bdblk * 64 + lane];
  for (int t0 = 0; t0 < CHUNK; t0 += 4) {
    const float4 dl = *(const float4*)(drow + t0);
    const float4 uu = *(const float4*)(urow + t0);
    const float4 Bv = *(const float4*)(Brow + t0);
    const float4 Cv = *(const float4*)(Crow + t0);
    const float dls[4] = {dl.x, dl.y, dl.z, dl.w};
    const float us[4] = {uu.x, uu.y, uu.z, uu.w};
    const float Bb[4] = {Bv.x, Bv.y, Bv.z, Bv.w};
    const float Cc[4] = {Cv.x, Cv.y, Cv.z, Cv.w};
#pragma unroll
    for (int j = 0; j < 4; ++j) {
      const float dA = __expf(dls[j] * A);
      s = fmaf(dA, s, dls[j] * us[j] * Bb[j]);
      float yc = s * Cc[j];
      yc += __shfl_xor(yc, 1, 64);
      yc += __shfl_xor(yc, 2, 64);
      yc += __shfl_xor(yc, 4, 64);
      yc += __shfl_xor(yc, 8, 64);
      if (n == 0) {
        const int t = t0 + j;
        const float zz = zrow[(size_t)t * DIM];
        grow[(size_t)t * DIM] = fmaf(us[j], Dprm, yc) * silu_f(zz);
      }
    }
  }
}

// ---------------- K4: out_proj GEMM ----------------
__global__ __launch_bounds__(256) void k4_outproj(
    const float* __restrict__ g, const float* __restrict__ wo,
    float* __restrict__ out) {
  __shared__ float As[16][68];
  __shared__ float Bs[16][68];
  const int tid = threadIdx.x;
  const int m0 = blockIdx.x * 64;
  const int n0 = blockIdx.y * 64;
  const int tx = tid & 15, ty = tid >> 4;
  const int lrow = tid >> 2, lcol = (tid & 3) * 4;
  const float* gp = g + (size_t)(n0 + lrow) * DIM + lcol;
  const float* wp = wo + (size_t)(m0 + lrow) * DIM + lcol;
  float acc[4][4] = {{0.f}};
  for (int k = 0; k < DIM; k += 16) {
    const float4 av = *(const float4*)(gp + k);
    const float4 bv = *(const float4*)(wp + k);
    __syncthreads();
    As[lcol + 0][lrow] = av.x; As[lcol + 1][lrow] = av.y;
    As[lcol + 2][lrow] = av.z; As[lcol + 3][lrow] = av.w;
    Bs[lcol + 0][lrow] = bv.x; Bs[lcol + 1][lrow] = bv.y;
    Bs[lcol + 2][lrow] = bv.z; Bs[lcol + 3][lrow] = bv.w;
    __syncthreads();
#pragma unroll
    for (int kk = 0; kk < 16; ++kk) {
      const float4 a = *(const float4*)&As[kk][ty * 4];
      const float4 b = *(const float4*)&Bs[kk][tx * 4];
      FMA_ROW(0, a.x) FMA_ROW(1, a.y) FMA_ROW(2, a.z) FMA_ROW(3, a.w)
    }
  }
#pragma unroll
  for (int i = 0; i < 4; ++i) {
    *(float4*)(out + (size_t)(n0 + ty * 4 + i) * DIM + m0 + tx * 4) =
        make_float4(acc[i][0], acc[i][1], acc[i][2], acc[i][3]);
  }
}

extern "C" void kernel_launch(void* const* d_in, const int* in_sizes, int n_in,
                              void* d_out, int out_size, void* d_ws,
                              size_t ws_size, hipStream_t stream) {
  const float* x          = (const float*)d_in[0];
  const float* in_proj_w  = (const float*)d_in[1];
  const float* conv_w     = (const float*)d_in[2];
  const float* conv_b     = (const float*)d_in[3];
  const float* A_log      = (const float*)d_in[4];
  const float* D_param    = (const float*)d_in[5];
  const float* x_proj_w   = (const float*)d_in[6];
  const float* dt_proj_w  = (const float*)d_in[7];
  const float* dt_proj_b  = (const float*)d_in[8];
  const float* out_proj_w = (const float*)d_in[9];
  float* out = (float*)d_out;
  float* ws = (float*)d_ws;

  const size_t PLANE = (size_t)BATCH * SEQ * DIM;  // 4M floats
  float* xcraw = ws;              // (b,d,t); dead after conv
  float* delta = ws;              // reuses xcraw region, (b,d,t)
  float* xc    = ws + PLANE;      // (b,d,t) post-conv
  float* zbuf  = ws + 2 * PLANE;  // (n,d)
  float* gbuf  = ws + 3 * PLANE;  // (n,d) gated scan output
  float* xdbl  = ws + 4 * PLANE;  // (b,96,t), 393216 floats
  float* scanP = xdbl + (size_t)BATCH * 96 * SEQ;   // LANES*NCH floats
  float* scanS = scanP + (size_t)LANES * NCH;       // LANES*NCH floats

  k1_inproj<<<dim3(64, 32), 256, 0, stream>>>(x, in_proj_w, xcraw, zbuf);
  k_conv<<<dim3((BATCH * DIM * SEQ / 4) / 256), 256, 0, stream>>>(
      xcraw, conv_w, conv_b, xc);
  k2_xproj<<<dim3(SEQ / 64, BATCH), 256, 0, stream>>>(xc, x_proj_w, xdbl);
  k3_dtproj<<<dim3(SEQ / 64, DIM / 64, BATCH), 256, 0, stream>>>(
      xdbl, dt_proj_w, dt_proj_b, delta);
  k_scan_pass1<<<dim3(512 * NCH), 64, 0, stream>>>(delta, xc, xdbl, A_log,
                                                   scanP, scanS);
  k_scan_mid<<<dim3(LANES / 64), 64, 0, stream>>>(scanP, scanS);
  k_scan_pass2<<<dim3(512 * NCH), 64, 0, stream>>>(delta, xc, xdbl, A_log,
                                                   D_param, zbuf, scanS, gbuf);
  k4_outproj<<<dim3(DIM / 64, BATCH * SEQ / 64), 256, 0, stream>>>(
      gbuf, out_proj_w, out);
}

// Round 3
// 500.631 us; speedup vs baseline: 3.0576x; 1.4856x over previous
//
#include <hip/hip_runtime.h>
#include <math.h>

#define BATCH 2
#define SEQ   2048
#define DIM   1024
#define NST   16
#define DTR   64
#define NCH   16                    // time chunks for the scan
#define CHUNK (SEQ / NCH)           // 128 steps per chunk
#define LANES (BATCH * DIM * NST)   // 32768 scan lanes

typedef _Float16 f16x8 __attribute__((ext_vector_type(8)));
typedef float f32x4 __attribute__((ext_vector_type(4)));

__device__ __forceinline__ float softplus_f(float v) {
  return fmaxf(v, 0.f) + log1pf(expf(-fabsf(v)));
}
__device__ __forceinline__ float silu_f(float v) {
  return v / (1.f + expf(-v));
}

__device__ __forceinline__ void gl_lds16(const _Float16* g, _Float16* l) {
  __builtin_amdgcn_global_load_lds(
      (const __attribute__((address_space(1))) void*)g,
      (__attribute__((address_space(3))) void*)l, 16, 0, 0);
}

#define FMA_ROW(i, av)                                        \
  acc[i][0] = fmaf(av, b.x, acc[i][0]);                       \
  acc[i][1] = fmaf(av, b.y, acc[i][1]);                       \
  acc[i][2] = fmaf(av, b.z, acc[i][2]);                       \
  acc[i][3] = fmaf(av, b.w, acc[i][3]);

// ---------------- split fp32 -> hi/lo f16 planes ----------------
__global__ __launch_bounds__(256) void k_cvt(const float* __restrict__ in,
                                             _Float16* __restrict__ hi,
                                             _Float16* __restrict__ lo,
                                             int n) {
  const int i = (blockIdx.x * 256 + threadIdx.x) * 8;
  if (i >= n) return;
  const float4 a = *(const float4*)(in + i);
  const float4 b = *(const float4*)(in + i + 4);
  const float v[8] = {a.x, a.y, a.z, a.w, b.x, b.y, b.z, b.w};
  f16x8 h, l;
#pragma unroll
  for (int j = 0; j < 8; ++j) {
    const _Float16 hh = (_Float16)v[j];
    h[j] = hh;
    l[j] = (_Float16)(v[j] - (float)hh);
  }
  *(f16x8*)(hi + i) = h;
  *(f16x8*)(lo + i) = l;
}

// ---------------- f16x3 NT GEMM: D[m][n] = sum_k A[m,k]*B[n,k], K=LD=1024 ----
// EPI 0: out0[m*1024 + n]   (k4: A=g rows n', B=wo rows m' -> out[n'*1024+m'])
// EPI 1: k1 split epilogue: m=c channel, n=b*2048+t
//        c<1024 -> xcraw[((n>>11)*1024+c)*2048 + (n&2047)], else z[n*1024+c-1024]
template <int EPI>
__global__ __launch_bounds__(256) void kgemm_f16x3(
    const _Float16* __restrict__ Ah, const _Float16* __restrict__ Al,
    const _Float16* __restrict__ Bh, const _Float16* __restrict__ Bl,
    float* __restrict__ out0, float* __restrict__ out1) {
  __shared__ _Float16 sm[16384];  // 32 KB: Ah|Al|Bh|Bl tiles, 128x32 packed
  _Float16* Ash = sm;
  _Float16* Asl = sm + 4096;
  _Float16* Bsh = sm + 8192;
  _Float16* Bsl = sm + 12288;

  const int tid = threadIdx.x;
  const int wid = tid >> 6, lane = tid & 63;
  const int wm = wid >> 1, wn = wid & 1;
  const int m0 = blockIdx.y * 128;
  const int n0 = blockIdx.x * 128;

  // staging: wave wid covers rows [wid*32, wid*32+32) of each plane
  const int r0 = wid * 32;
  const int srow = lane >> 2;
  const int skq = (lane & 3) * 8;
  const _Float16* gAh = Ah + (size_t)(m0 + r0 + srow) * 1024 + skq;
  const _Float16* gAl = Al + (size_t)(m0 + r0 + srow) * 1024 + skq;
  const _Float16* gBh = Bh + (size_t)(n0 + r0 + srow) * 1024 + skq;
  const _Float16* gBl = Bl + (size_t)(n0 + r0 + srow) * 1024 + skq;
  _Float16* lAh = Ash + r0 * 32;
  _Float16* lAl = Asl + r0 * 32;
  _Float16* lBh = Bsh + r0 * 32;
  _Float16* lBl = Bsl + r0 * 32;

  const int fr = lane & 15;
  const int fk = (lane >> 4) * 8;

  f32x4 acc[4][4];
#pragma unroll
  for (int i = 0; i < 4; ++i)
#pragma unroll
    for (int j = 0; j < 4; ++j) acc[i][j] = (f32x4)(0.f);

  for (int k0 = 0; k0 < 1024; k0 += 32) {
    __syncthreads();
    gl_lds16(gAh + k0, lAh);
    gl_lds16(gAh + k0 + 16 * 1024, lAh + 512);
    gl_lds16(gAl + k0, lAl);
    gl_lds16(gAl + k0 + 16 * 1024, lAl + 512);
    gl_lds16(gBh + k0, lBh);
    gl_lds16(gBh + k0 + 16 * 1024, lBh + 512);
    gl_lds16(gBl + k0, lBl);
    gl_lds16(gBl + k0 + 16 * 1024, lBl + 512);
    __syncthreads();

    f16x8 ah[4], alo[4], bh[4], blo[4];
#pragma unroll
    for (int i = 0; i < 4; ++i) {
      const int ao = (wm * 64 + i * 16 + fr) * 32 + fk;
      const int bo = (wn * 64 + i * 16 + fr) * 32 + fk;
      ah[i]  = *(const f16x8*)(Ash + ao);
      alo[i] = *(const f16x8*)(Asl + ao);
      bh[i]  = *(const f16x8*)(Bsh + bo);
      blo[i] = *(const f16x8*)(Bsl + bo);
    }
#pragma unroll
    for (int i = 0; i < 4; ++i)
#pragma unroll
      for (int j = 0; j < 4; ++j) {
        acc[i][j] = __builtin_amdgcn_mfma_f32_16x16x32_f16(ah[i], bh[j],
                                                           acc[i][j], 0, 0, 0);
        acc[i][j] = __builtin_amdgcn_mfma_f32_16x16x32_f16(ah[i], blo[j],
                                                           acc[i][j], 0, 0, 0);
        acc[i][j] = __builtin_amdgcn_mfma_f32_16x16x32_f16(alo[i], bh[j],
                                                           acc[i][j], 0, 0, 0);
      }
  }

  const int lr4 = (lane >> 4) * 4, lc = lane & 15;
#pragma unroll
  for (int i = 0; i < 4; ++i) {
#pragma unroll
    for (int j = 0; j < 4; ++j) {
      const int ar = m0 + wm * 64 + i * 16 + lr4;
      const int bc = n0 + wn * 64 + j * 16 + lc;
#pragma unroll
      for (int r = 0; r < 4; ++r) {
        const float v = acc[i][j][r];
        if (EPI == 0) {
          out0[(size_t)(ar + r) * 1024 + bc] = v;
        } else {
          if (ar < 1024) {  // block-uniform (tile boundary aligned to 1024)
            out0[((size_t)(bc >> 11) * 1024 + ar + r) * 2048 + (bc & 2047)] = v;
          } else {
            out1[(size_t)bc * 1024 + (ar + r - 1024)] = v;
          }
        }
      }
    }
  }
}

// ---------------- conv: depthwise k=3, pad=1, along t ----------------
__global__ __launch_bounds__(256) void k_conv(
    const float* __restrict__ xcraw, const float* __restrict__ cw,
    const float* __restrict__ cb, float* __restrict__ xc) {
  const int idx = blockIdx.x * 256 + threadIdx.x;
  const int t0 = (idx & (SEQ / 4 - 1)) * 4;
  const int r = idx >> 9;  // b*DIM + d
  const int d = r & (DIM - 1);
  const float w0 = cw[d * 3 + 0], w1 = cw[d * 3 + 1], w2 = cw[d * 3 + 2];
  const float bias = cb[d];
  const float* in = xcraw + (size_t)r * SEQ;
  float o[4];
#pragma unroll
  for (int j = 0; j < 4; ++j) {
    const int t = t0 + j;
    const float xm = (t > 0) ? in[t - 1] : 0.f;
    const float x0 = in[t];
    const float xp = (t < SEQ - 1) ? in[t + 1] : 0.f;
    o[j] = fmaf(w0, xm, fmaf(w1, x0, fmaf(w2, xp, bias)));
  }
  *(float4*)(xc + (size_t)r * SEQ + t0) = make_float4(o[0], o[1], o[2], o[3]);
}

// ---------------- K2: x_proj GEMM (fp32, small) ----------------
__global__ __launch_bounds__(256) void k2_xproj(
    const float* __restrict__ xc, const float* __restrict__ wp,
    float* __restrict__ xdbl) {
  __shared__ float As[16][96];
  __shared__ float Bs[16][68];
  const int tid = threadIdx.x;
  const int b = blockIdx.y;
  const int t0 = blockIdx.x * 64;
  const int tx = tid & 15, ty = tid >> 4;
  const int bk = tid >> 4, bt4 = (tid & 15) * 4;
  float acc[6][4] = {{0.f}};
  for (int k = 0; k < DIM; k += 16) {
    float a_reg[6];
#pragma unroll
    for (int i = 0; i < 6; ++i) {
      const int ii = tid + 256 * i;
      a_reg[i] = wp[(size_t)(ii >> 4) * DIM + k + (ii & 15)];
    }
    const float4 bv =
        *(const float4*)(xc + ((size_t)b * DIM + k + bk) * SEQ + t0 + bt4);
    __syncthreads();
#pragma unroll
    for (int i = 0; i < 6; ++i) {
      const int ii = tid + 256 * i;
      As[ii & 15][ii >> 4] = a_reg[i];
    }
    Bs[bk][bt4 + 0] = bv.x; Bs[bk][bt4 + 1] = bv.y;
    Bs[bk][bt4 + 2] = bv.z; Bs[bk][bt4 + 3] = bv.w;
    __syncthreads();
#pragma unroll
    for (int kk = 0; kk < 16; ++kk) {
      const float4 b4 = *(const float4*)&Bs[kk][tx * 4];
#pragma unroll
      for (int i = 0; i < 6; ++i) {
        const float a = As[kk][ty + 16 * i];
        acc[i][0] = fmaf(a, b4.x, acc[i][0]);
        acc[i][1] = fmaf(a, b4.y, acc[i][1]);
        acc[i][2] = fmaf(a, b4.z, acc[i][2]);
        acc[i][3] = fmaf(a, b4.w, acc[i][3]);
      }
    }
  }
#pragma unroll
  for (int i = 0; i < 6; ++i) {
    const int j = ty + 16 * i;
    *(float4*)(xdbl + ((size_t)b * 96 + j) * SEQ + t0 + tx * 4) =
        make_float4(acc[i][0], acc[i][1], acc[i][2], acc[i][3]);
  }
}

// ---------------- K3: dt_proj GEMM + softplus (fp32, small) ----------------
__global__ __launch_bounds__(256) void k3_dtproj(
    const float* __restrict__ xdbl, const float* __restrict__ dtw,
    const float* __restrict__ dtb, float* __restrict__ delta) {
  __shared__ float As[16][68];
  __shared__ float Bs[16][68];
  const int tid = threadIdx.x;
  const int b = blockIdx.z;
  const int d0 = blockIdx.y * 64;
  const int t0 = blockIdx.x * 64;
  const int tx = tid & 15, ty = tid >> 4;
  const int lrow = tid >> 2, lcol = (tid & 3) * 4;
  const int bk = tid >> 4, bt4 = (tid & 15) * 4;
  float acc[4][4] = {{0.f}};
  for (int k = 0; k < DTR; k += 16) {
    const float4 av =
        *(const float4*)(dtw + (size_t)(d0 + lrow) * DTR + k + lcol);
    const float4 bv =
        *(const float4*)(xdbl + ((size_t)b * 96 + k + bk) * SEQ + t0 + bt4);
    __syncthreads();
    As[lcol + 0][lrow] = av.x; As[lcol + 1][lrow] = av.y;
    As[lcol + 2][lrow] = av.z; As[lcol + 3][lrow] = av.w;
    Bs[bk][bt4 + 0] = bv.x; Bs[bk][bt4 + 1] = bv.y;
    Bs[bk][bt4 + 2] = bv.z; Bs[bk][bt4 + 3] = bv.w;
    __syncthreads();
#pragma unroll
    for (int kk = 0; kk < 16; ++kk) {
      const float4 a = *(const float4*)&As[kk][ty * 4];
      const float4 b = *(const float4*)&Bs[kk][tx * 4];
      FMA_ROW(0, a.x) FMA_ROW(1, a.y) FMA_ROW(2, a.z) FMA_ROW(3, a.w)
    }
  }
#pragma unroll
  for (int i = 0; i < 4; ++i) {
    const int d = d0 + ty * 4 + i;
    const float bias = dtb[d];
    float4 v;
    v.x = softplus_f(acc[i][0] + bias);
    v.y = softplus_f(acc[i][1] + bias);
    v.z = softplus_f(acc[i][2] + bias);
    v.w = softplus_f(acc[i][3] + bias);
    *(float4*)(delta + ((size_t)b * DIM + d) * SEQ + t0 + tx * 4) = v;
  }
}

// ---------------- scan pass 1: per-chunk product + local end state ----------
__global__ __launch_bounds__(64) void k_scan_pass1(
    const float* __restrict__ delta, const float* __restrict__ u,
    const float* __restrict__ xdbl, const float* __restrict__ A_log,
    float* __restrict__ Pbuf, float* __restrict__ Sbuf) {
  const int lane = threadIdx.x;
  const int grp = lane >> 4, n = lane & 15;
  const int bdblk = blockIdx.x & 511;
  const int chunk = blockIdx.x >> 9;
  const int idx = bdblk * 4 + grp;  // b*DIM + d
  const int b = idx >> 10, d = idx & (DIM - 1);
  const float A = -expf(A_log[d * NST + n]);
  const int tc = chunk * CHUNK;
  const float* drow = delta + (size_t)idx * SEQ + tc;
  const float* urow = u + (size_t)idx * SEQ + tc;
  const float* Brow = xdbl + ((size_t)b * 96 + DTR + n) * SEQ + tc;
  float s = 0.f, dsum = 0.f;
  for (int t0 = 0; t0 < CHUNK; t0 += 4) {
    const float4 dl = *(const float4*)(drow + t0);
    const float4 uu = *(const float4*)(urow + t0);
    const float4 Bv = *(const float4*)(Brow + t0);
    const float dls[4] = {dl.x, dl.y, dl.z, dl.w};
    const float us[4] = {uu.x, uu.y, uu.z, uu.w};
    const float Bb[4] = {Bv.x, Bv.y, Bv.z, Bv.w};
#pragma unroll
    for (int j = 0; j < 4; ++j) {
      dsum += dls[j];
      const float dA = __expf(dls[j] * A);
      s = fmaf(dA, s, dls[j] * us[j] * Bb[j]);
    }
  }
  const int gi = chunk * LANES + bdblk * 64 + lane;
  Pbuf[gi] = __expf(dsum * A);
  Sbuf[gi] = s;
}

// ---------------- scan mid ----------------
__global__ __launch_bounds__(64) void k_scan_mid(
    const float* __restrict__ Pbuf, float* __restrict__ Sbuf) {
  const int gl = blockIdx.x * 64 + threadIdx.x;
  float run = 0.f;
#pragma unroll
  for (int c = 0; c < NCH; ++c) {
    const float p = Pbuf[c * LANES + gl];
    const float s = Sbuf[c * LANES + gl];
    Sbuf[c * LANES + gl] = run;
    run = fmaf(p, run, s);
  }
}

// ---------------- scan pass 2: seeded scan + reduce + gate; g as hi/lo f16 ---
__global__ __launch_bounds__(64) void k_scan_pass2(
    const float* __restrict__ delta, const float* __restrict__ u,
    const float* __restrict__ xdbl, const float* __restrict__ A_log,
    const float* __restrict__ Dp, const float* __restrict__ z,
    const float* __restrict__ sInit, _Float16* __restrict__ gh,
    _Float16* __restrict__ gl) {
  const int lane = threadIdx.x;
  const int grp = lane >> 4, n = lane & 15;
  const int bdblk = blockIdx.x & 511;
  const int chunk = blockIdx.x >> 9;
  const int idx = bdblk * 4 + grp;  // b*DIM + d
  const int b = idx >> 10, d = idx & (DIM - 1);
  const float A = -expf(A_log[d * NST + n]);
  const float Dprm = Dp[d];
  const int tc = chunk * CHUNK;
  const float* drow = delta + (size_t)idx * SEQ + tc;
  const float* urow = u + (size_t)idx * SEQ + tc;
  const float* Brow = xdbl + ((size_t)b * 96 + DTR + n) * SEQ + tc;
  const float* Crow = xdbl + ((size_t)b * 96 + DTR + NST + n) * SEQ + tc;
  const size_t gbase = ((size_t)b * SEQ + tc) * DIM + d;
  const float* zrow = z + gbase;
  float s = sInit[chunk * LANES + bdblk * 64 + lane];
  for (int t0 = 0; t0 < CHUNK; t0 += 4) {
    const float4 dl = *(const float4*)(drow + t0);
    const float4 uu = *(const float4*)(urow + t0);
    const float4 Bv = *(const float4*)(Brow + t0);
    const float4 Cv = *(const float4*)(Crow + t0);
    const float dls[4] = {dl.x, dl.y, dl.z, dl.w};
    const float us[4] = {uu.x, uu.y, uu.z, uu.w};
    const float Bb[4] = {Bv.x, Bv.y, Bv.z, Bv.w};
    const float Cc[4] = {Cv.x, Cv.y, Cv.z, Cv.w};
#pragma unroll
    for (int j = 0; j < 4; ++j) {
      const float dA = __expf(dls[j] * A);
      s = fmaf(dA, s, dls[j] * us[j] * Bb[j]);
      float yc = s * Cc[j];
      yc += __shfl_xor(yc, 1, 64);
      yc += __shfl_xor(yc, 2, 64);
      yc += __shfl_xor(yc, 4, 64);
      yc += __shfl_xor(yc, 8, 64);
      if (n == 0) {
        const int t = t0 + j;
        const float zz = zrow[(size_t)t * DIM];
        const float gv = fmaf(us[j], Dprm, yc) * silu_f(zz);
        const _Float16 h = (_Float16)gv;
        gh[gbase + (size_t)t * DIM] = h;
        gl[gbase + (size_t)t * DIM] = (_Float16)(gv - (float)h);
      }
    }
  }
}

extern "C" void kernel_launch(void* const* d_in, const int* in_sizes, int n_in,
                              void* d_out, int out_size, void* d_ws,
                              size_t ws_size, hipStream_t stream) {
  const float* x          = (const float*)d_in[0];
  const float* in_proj_w  = (const float*)d_in[1];
  const float* conv_w     = (const float*)d_in[2];
  const float* conv_b     = (const float*)d_in[3];
  const float* A_log      = (const float*)d_in[4];
  const float* D_param    = (const float*)d_in[5];
  const float* x_proj_w   = (const float*)d_in[6];
  const float* dt_proj_w  = (const float*)d_in[7];
  const float* dt_proj_b  = (const float*)d_in[8];
  const float* out_proj_w = (const float*)d_in[9];
  float* out = (float*)d_out;
  float* ws = (float*)d_ws;

  const size_t PLANE = (size_t)BATCH * SEQ * DIM;  // 4M floats (16 MB)
  float* xcraw = ws;              // (b,d,t); later reused as delta
  float* delta = ws;
  float* xc    = ws + PLANE;      // (b,d,t) post-conv
  float* zbuf  = ws + 2 * PLANE;  // (n,d)
  // plane 3: x hi/lo f16 planes; dead after kgemm<1>, then reused as g hi/lo
  _Float16* xh = (_Float16*)(ws + 3 * PLANE);
  _Float16* xl = (_Float16*)(ws + 3 * PLANE + PLANE / 2);
  _Float16* gh = xh;
  _Float16* gl = xl;
  float* xdbl  = ws + 4 * PLANE;                    // (b,96,t) 393216 floats
  float* scanP = xdbl + (size_t)BATCH * 96 * SEQ;   // 524288 floats
  float* scanS = scanP + (size_t)LANES * NCH;       // 524288 floats
  // weights hi/lo after the scan buffers (3M floats); total ws ~86 MB
  _Float16* wih = (_Float16*)(ws + 4 * PLANE + 1572864);
  _Float16* wil = wih + (size_t)2 * DIM * DIM;
  _Float16* woh = wil + (size_t)2 * DIM * DIM;
  _Float16* wol = woh + (size_t)DIM * DIM;

  k_cvt<<<dim3(2048), 256, 0, stream>>>(x, xh, xl, BATCH * SEQ * DIM);
  k_cvt<<<dim3(1024), 256, 0, stream>>>(in_proj_w, wih, wil, 2 * DIM * DIM);
  k_cvt<<<dim3(512), 256, 0, stream>>>(out_proj_w, woh, wol, DIM * DIM);

  // k1: A=in_proj_w (M=2048 rows c), B=x (N=4096 rows n)
  kgemm_f16x3<1><<<dim3(32, 16), 256, 0, stream>>>(wih, wil, xh, xl,
                                                   xcraw, zbuf);
  k_conv<<<dim3((BATCH * DIM * SEQ / 4) / 256), 256, 0, stream>>>(
      xcraw, conv_w, conv_b, xc);
  k2_xproj<<<dim3(SEQ / 64, BATCH), 256, 0, stream>>>(xc, x_proj_w, xdbl);
  k3_dtproj<<<dim3(SEQ / 64, DIM / 64, BATCH), 256, 0, stream>>>(
      xdbl, dt_proj_w, dt_proj_b, delta);
  k_scan_pass1<<<dim3(512 * NCH), 64, 0, stream>>>(delta, xc, xdbl, A_log,
                                                   scanP, scanS);
  k_scan_mid<<<dim3(LANES / 64), 64, 0, stream>>>(scanP, scanS);
  k_scan_pass2<<<dim3(512 * NCH), 64, 0, stream>>>(delta, xc, xdbl, A_log,
                                                   D_param, zbuf, scanS,
                                                   gh, gl);
  // k4: A=g (M=4096 rows n), B=out_proj_w (N=1024 rows m) -> out[n*1024+m]
  kgemm_f16x3<0><<<dim3(8, 32), 256, 0, stream>>>(gh, gl, woh, wol,
                                                  out, nullptr);
}

// Round 4
// 475.148 us; speedup vs baseline: 3.2216x; 1.0536x over previous
//
#include <hip/hip_runtime.h>
#include <math.h>

#define BATCH 2
#define SEQ   2048
#define DIM   1024
#define NST   16
#define DTR   64
#define NCH   16                    // time chunks for the scan
#define CHUNK (SEQ / NCH)           // 128 steps per chunk
#define LANES (BATCH * DIM * NST)   // 32768 scan lanes

typedef _Float16 f16x8 __attribute__((ext_vector_type(8)));
typedef float f32x4 __attribute__((ext_vector_type(4)));

__device__ __forceinline__ float softplus_f(float v) {
  return fmaxf(v, 0.f) + log1pf(expf(-fabsf(v)));
}
__device__ __forceinline__ float silu_f(float v) {
  return v / (1.f + expf(-v));
}

__device__ __forceinline__ void gl_lds16(const _Float16* g, _Float16* l) {
  __builtin_amdgcn_global_load_lds(
      (const __attribute__((address_space(1))) void*)g,
      (__attribute__((address_space(3))) void*)l, 16, 0, 0);
}

#define FMA_ROW(i, av)                                        \
  acc[i][0] = fmaf(av, b.x, acc[i][0]);                       \
  acc[i][1] = fmaf(av, b.y, acc[i][1]);                       \
  acc[i][2] = fmaf(av, b.z, acc[i][2]);                       \
  acc[i][3] = fmaf(av, b.w, acc[i][3]);

// ---------------- split fp32 -> hi/lo f16 planes ----------------
__global__ __launch_bounds__(256) void k_cvt(const float* __restrict__ in,
                                             _Float16* __restrict__ hi,
                                             _Float16* __restrict__ lo,
                                             int n) {
  const int i = (blockIdx.x * 256 + threadIdx.x) * 8;
  if (i >= n) return;
  const float4 a = *(const float4*)(in + i);
  const float4 b = *(const float4*)(in + i + 4);
  const float v[8] = {a.x, a.y, a.z, a.w, b.x, b.y, b.z, b.w};
  f16x8 h, l;
#pragma unroll
  for (int j = 0; j < 8; ++j) {
    const _Float16 hh = (_Float16)v[j];
    h[j] = hh;
    l[j] = (_Float16)(v[j] - (float)hh);
  }
  *(f16x8*)(hi + i) = h;
  *(f16x8*)(lo + i) = l;
}

// ---------------- f16x3 NT GEMM: D[m][n] = sum_k A[m,k]*B[n,k], K=LD=1024 ----
// EPI 0: out0[m*1024 + n]
// EPI 1: k1 split epilogue, channel-major both halves: m=c, n=b*2048+t
//        c<1024 -> xcraw[((n>>11)*1024+c)*2048 + t], else zbuf same form
template <int EPI>
__global__ __launch_bounds__(256) void kgemm_f16x3(
    const _Float16* __restrict__ Ah, const _Float16* __restrict__ Al,
    const _Float16* __restrict__ Bh, const _Float16* __restrict__ Bl,
    float* __restrict__ out0, float* __restrict__ out1) {
  __shared__ _Float16 sm[16384];  // 32 KB: Ah|Al|Bh|Bl tiles, 128x32 packed
  _Float16* Ash = sm;
  _Float16* Asl = sm + 4096;
  _Float16* Bsh = sm + 8192;
  _Float16* Bsl = sm + 12288;

  const int tid = threadIdx.x;
  const int wid = tid >> 6, lane = tid & 63;
  const int wm = wid >> 1, wn = wid & 1;
  const int m0 = blockIdx.y * 128;
  const int n0 = blockIdx.x * 128;

  const int r0 = wid * 32;
  const int srow = lane >> 2;
  const int skq = (lane & 3) * 8;
  const _Float16* gAh = Ah + (size_t)(m0 + r0 + srow) * 1024 + skq;
  const _Float16* gAl = Al + (size_t)(m0 + r0 + srow) * 1024 + skq;
  const _Float16* gBh = Bh + (size_t)(n0 + r0 + srow) * 1024 + skq;
  const _Float16* gBl = Bl + (size_t)(n0 + r0 + srow) * 1024 + skq;
  _Float16* lAh = Ash + r0 * 32;
  _Float16* lAl = Asl + r0 * 32;
  _Float16* lBh = Bsh + r0 * 32;
  _Float16* lBl = Bsl + r0 * 32;

  const int fr = lane & 15;
  const int fk = (lane >> 4) * 8;

  f32x4 acc[4][4];
#pragma unroll
  for (int i = 0; i < 4; ++i)
#pragma unroll
    for (int j = 0; j < 4; ++j) acc[i][j] = (f32x4)(0.f);

  for (int k0 = 0; k0 < 1024; k0 += 32) {
    __syncthreads();
    gl_lds16(gAh + k0, lAh);
    gl_lds16(gAh + k0 + 16 * 1024, lAh + 512);
    gl_lds16(gAl + k0, lAl);
    gl_lds16(gAl + k0 + 16 * 1024, lAl + 512);
    gl_lds16(gBh + k0, lBh);
    gl_lds16(gBh + k0 + 16 * 1024, lBh + 512);
    gl_lds16(gBl + k0, lBl);
    gl_lds16(gBl + k0 + 16 * 1024, lBl + 512);
    __syncthreads();

    f16x8 ah[4], alo[4], bh[4], blo[4];
#pragma unroll
    for (int i = 0; i < 4; ++i) {
      const int ao = (wm * 64 + i * 16 + fr) * 32 + fk;
      const int bo = (wn * 64 + i * 16 + fr) * 32 + fk;
      ah[i]  = *(const f16x8*)(Ash + ao);
      alo[i] = *(const f16x8*)(Asl + ao);
      bh[i]  = *(const f16x8*)(Bsh + bo);
      blo[i] = *(const f16x8*)(Bsl + bo);
    }
#pragma unroll
    for (int i = 0; i < 4; ++i)
#pragma unroll
      for (int j = 0; j < 4; ++j) {
        acc[i][j] = __builtin_amdgcn_mfma_f32_16x16x32_f16(ah[i], bh[j],
                                                           acc[i][j], 0, 0, 0);
        acc[i][j] = __builtin_amdgcn_mfma_f32_16x16x32_f16(ah[i], blo[j],
                                                           acc[i][j], 0, 0, 0);
        acc[i][j] = __builtin_amdgcn_mfma_f32_16x16x32_f16(alo[i], bh[j],
                                                           acc[i][j], 0, 0, 0);
      }
  }

  const int lr4 = (lane >> 4) * 4, lc = lane & 15;
#pragma unroll
  for (int i = 0; i < 4; ++i) {
#pragma unroll
    for (int j = 0; j < 4; ++j) {
      const int ar = m0 + wm * 64 + i * 16 + lr4;
      const int bc = n0 + wn * 64 + j * 16 + lc;
#pragma unroll
      for (int r = 0; r < 4; ++r) {
        const float v = acc[i][j][r];
        if (EPI == 0) {
          out0[(size_t)(ar + r) * 1024 + bc] = v;
        } else {
          const int bb = bc >> 11, tt = bc & 2047;
          if (ar < 1024) {  // block-uniform (tile boundary aligned to 1024)
            out0[((size_t)bb * 1024 + ar + r) * 2048 + tt] = v;
          } else {
            out1[((size_t)bb * 1024 + (ar + r - 1024)) * 2048 + tt] = v;
          }
        }
      }
    }
  }
}

// ---------------- conv: depthwise k=3, pad=1, along t ----------------
__global__ __launch_bounds__(256) void k_conv(
    const float* __restrict__ xcraw, const float* __restrict__ cw,
    const float* __restrict__ cb, float* __restrict__ xc) {
  const int idx = blockIdx.x * 256 + threadIdx.x;
  const int t0 = (idx & (SEQ / 4 - 1)) * 4;
  const int r = idx >> 9;  // b*DIM + d
  const int d = r & (DIM - 1);
  const float w0 = cw[d * 3 + 0], w1 = cw[d * 3 + 1], w2 = cw[d * 3 + 2];
  const float bias = cb[d];
  const float* in = xcraw + (size_t)r * SEQ;
  float o[4];
#pragma unroll
  for (int j = 0; j < 4; ++j) {
    const int t = t0 + j;
    const float xm = (t > 0) ? in[t - 1] : 0.f;
    const float x0 = in[t];
    const float xp = (t < SEQ - 1) ? in[t + 1] : 0.f;
    o[j] = fmaf(w0, xm, fmaf(w1, x0, fmaf(w2, xp, bias)));
  }
  *(float4*)(xc + (size_t)r * SEQ + t0) = make_float4(o[0], o[1], o[2], o[3]);
}

// ---------------- K2: x_proj GEMM (fp32, small) ----------------
__global__ __launch_bounds__(256) void k2_xproj(
    const float* __restrict__ xc, const float* __restrict__ wp,
    float* __restrict__ xdbl) {
  __shared__ float As[16][96];
  __shared__ float Bs[16][68];
  const int tid = threadIdx.x;
  const int b = blockIdx.y;
  const int t0 = blockIdx.x * 64;
  const int tx = tid & 15, ty = tid >> 4;
  const int bk = tid >> 4, bt4 = (tid & 15) * 4;
  float acc[6][4] = {{0.f}};
  for (int k = 0; k < DIM; k += 16) {
    float a_reg[6];
#pragma unroll
    for (int i = 0; i < 6; ++i) {
      const int ii = tid + 256 * i;
      a_reg[i] = wp[(size_t)(ii >> 4) * DIM + k + (ii & 15)];
    }
    const float4 bv =
        *(const float4*)(xc + ((size_t)b * DIM + k + bk) * SEQ + t0 + bt4);
    __syncthreads();
#pragma unroll
    for (int i = 0; i < 6; ++i) {
      const int ii = tid + 256 * i;
      As[ii & 15][ii >> 4] = a_reg[i];
    }
    Bs[bk][bt4 + 0] = bv.x; Bs[bk][bt4 + 1] = bv.y;
    Bs[bk][bt4 + 2] = bv.z; Bs[bk][bt4 + 3] = bv.w;
    __syncthreads();
#pragma unroll
    for (int kk = 0; kk < 16; ++kk) {
      const float4 b4 = *(const float4*)&Bs[kk][tx * 4];
#pragma unroll
      for (int i = 0; i < 6; ++i) {
        const float a = As[kk][ty + 16 * i];
        acc[i][0] = fmaf(a, b4.x, acc[i][0]);
        acc[i][1] = fmaf(a, b4.y, acc[i][1]);
        acc[i][2] = fmaf(a, b4.z, acc[i][2]);
        acc[i][3] = fmaf(a, b4.w, acc[i][3]);
      }
    }
  }
#pragma unroll
  for (int i = 0; i < 6; ++i) {
    const int j = ty + 16 * i;
    *(float4*)(xdbl + ((size_t)b * 96 + j) * SEQ + t0 + tx * 4) =
        make_float4(acc[i][0], acc[i][1], acc[i][2], acc[i][3]);
  }
}

// ---------------- K3: dt_proj GEMM + softplus (fp32, small) ----------------
__global__ __launch_bounds__(256) void k3_dtproj(
    const float* __restrict__ xdbl, const float* __restrict__ dtw,
    const float* __restrict__ dtb, float* __restrict__ delta) {
  __shared__ float As[16][68];
  __shared__ float Bs[16][68];
  const int tid = threadIdx.x;
  const int b = blockIdx.z;
  const int d0 = blockIdx.y * 64;
  const int t0 = blockIdx.x * 64;
  const int tx = tid & 15, ty = tid >> 4;
  const int lrow = tid >> 2, lcol = (tid & 3) * 4;
  const int bk = tid >> 4, bt4 = (tid & 15) * 4;
  float acc[4][4] = {{0.f}};
  for (int k = 0; k < DTR; k += 16) {
    const float4 av =
        *(const float4*)(dtw + (size_t)(d0 + lrow) * DTR + k + lcol);
    const float4 bv =
        *(const float4*)(xdbl + ((size_t)b * 96 + k + bk) * SEQ + t0 + bt4);
    __syncthreads();
    As[lcol + 0][lrow] = av.x; As[lcol + 1][lrow] = av.y;
    As[lcol + 2][lrow] = av.z; As[lcol + 3][lrow] = av.w;
    Bs[bk][bt4 + 0] = bv.x; Bs[bk][bt4 + 1] = bv.y;
    Bs[bk][bt4 + 2] = bv.z; Bs[bk][bt4 + 3] = bv.w;
    __syncthreads();
#pragma unroll
    for (int kk = 0; kk < 16; ++kk) {
      const float4 a = *(const float4*)&As[kk][ty * 4];
      const float4 b = *(const float4*)&Bs[kk][tx * 4];
      FMA_ROW(0, a.x) FMA_ROW(1, a.y) FMA_ROW(2, a.z) FMA_ROW(3, a.w)
    }
  }
#pragma unroll
  for (int i = 0; i < 4; ++i) {
    const int d = d0 + ty * 4 + i;
    const float bias = dtb[d];
    float4 v;
    v.x = softplus_f(acc[i][0] + bias);
    v.y = softplus_f(acc[i][1] + bias);
    v.z = softplus_f(acc[i][2] + bias);
    v.w = softplus_f(acc[i][3] + bias);
    *(float4*)(delta + ((size_t)b * DIM + d) * SEQ + t0 + tx * 4) = v;
  }
}

// ---------------- scan pass 1: per-chunk product + local end state ----------
__global__ __launch_bounds__(64) void k_scan_pass1(
    const float* __restrict__ delta, const float* __restrict__ u,
    const float* __restrict__ xdbl, const float* __restrict__ A_log,
    float* __restrict__ Pbuf, float* __restrict__ Sbuf) {
  const int lane = threadIdx.x;
  const int grp = lane >> 4, n = lane & 15;
  const int bdblk = blockIdx.x & 511;
  const int chunk = blockIdx.x >> 9;
  const int idx = bdblk * 4 + grp;  // b*DIM + d
  const int b = idx >> 10, d = idx & (DIM - 1);
  const float A = -expf(A_log[d * NST + n]);
  const int tc = chunk * CHUNK;
  const float* drow = delta + (size_t)idx * SEQ + tc;
  const float* urow = u + (size_t)idx * SEQ + tc;
  const float* Brow = xdbl + ((size_t)b * 96 + DTR + n) * SEQ + tc;
  float s = 0.f, dsum = 0.f;
  for (int t0 = 0; t0 < CHUNK; t0 += 4) {
    const float4 dl = *(const float4*)(drow + t0);
    const float4 uu = *(const float4*)(urow + t0);
    const float4 Bv = *(const float4*)(Brow + t0);
    const float dls[4] = {dl.x, dl.y, dl.z, dl.w};
    const float us[4] = {uu.x, uu.y, uu.z, uu.w};
    const float Bb[4] = {Bv.x, Bv.y, Bv.z, Bv.w};
#pragma unroll
    for (int j = 0; j < 4; ++j) {
      dsum += dls[j];
      const float dA = __expf(dls[j] * A);
      s = fmaf(dA, s, dls[j] * us[j] * Bb[j]);
    }
  }
  const int gi = chunk * LANES + bdblk * 64 + lane;
  Pbuf[gi] = __expf(dsum * A);
  Sbuf[gi] = s;
}

// ---------------- scan mid ----------------
__global__ __launch_bounds__(64) void k_scan_mid(
    const float* __restrict__ Pbuf, float* __restrict__ Sbuf) {
  const int gl = blockIdx.x * 64 + threadIdx.x;
  float run = 0.f;
#pragma unroll
  for (int c = 0; c < NCH; ++c) {
    const float p = Pbuf[c * LANES + gl];
    const float s = Sbuf[c * LANES + gl];
    Sbuf[c * LANES + gl] = run;
    run = fmaf(p, run, s);
  }
}

// ---------------- scan pass 2: seeded scan + reduce; y (b,d,t) coalesced ----
// After the xor-butterfly the n-sum is in all 16 lanes of the group; lane n
// keeps t = tw+n of each 16-t window, so the store is 16 contiguous floats
// per group. u*D folded here (u is broadcast across the group's lanes).
__global__ __launch_bounds__(64) void k_scan_pass2(
    const float* __restrict__ delta, const float* __restrict__ u,
    const float* __restrict__ xdbl, const float* __restrict__ A_log,
    const float* __restrict__ Dp, const float* __restrict__ sInit,
    float* __restrict__ y) {
  const int lane = threadIdx.x;
  const int grp = lane >> 4, n = lane & 15;
  const int bdblk = blockIdx.x & 511;
  const int chunk = blockIdx.x >> 9;
  const int idx = bdblk * 4 + grp;  // b*DIM + d
  const int b = idx >> 10, d = idx & (DIM - 1);
  const float A = -expf(A_log[d * NST + n]);
  const float Dprm = Dp[d];
  const int tc = chunk * CHUNK;
  const float* drow = delta + (size_t)idx * SEQ + tc;
  const float* urow = u + (size_t)idx * SEQ + tc;
  const float* Brow = xdbl + ((size_t)b * 96 + DTR + n) * SEQ + tc;
  const float* Crow = xdbl + ((size_t)b * 96 + DTR + NST + n) * SEQ + tc;
  float* yrow = y + (size_t)idx * SEQ + tc;
  float s = sInit[chunk * LANES + bdblk * 64 + lane];
  for (int tw = 0; tw < CHUNK; tw += 16) {
    float ykeep = 0.f;
#pragma unroll
    for (int q = 0; q < 4; ++q) {
      const int t0 = tw + q * 4;
      const float4 dl = *(const float4*)(drow + t0);
      const float4 uu = *(const float4*)(urow + t0);
      const float4 Bv = *(const float4*)(Brow + t0);
      const float4 Cv = *(const float4*)(Crow + t0);
      const float dls[4] = {dl.x, dl.y, dl.z, dl.w};
      const float us[4] = {uu.x, uu.y, uu.z, uu.w};
      const float Bb[4] = {Bv.x, Bv.y, Bv.z, Bv.w};
      const float Cc[4] = {Cv.x, Cv.y, Cv.z, Cv.w};
#pragma unroll
      for (int j = 0; j < 4; ++j) {
        const float dA = __expf(dls[j] * A);
        s = fmaf(dA, s, dls[j] * us[j] * Bb[j]);
        float yc = s * Cc[j];
        yc += __shfl_xor(yc, 1, 64);
        yc += __shfl_xor(yc, 2, 64);
        yc += __shfl_xor(yc, 4, 64);
        yc += __shfl_xor(yc, 8, 64);
        if (q * 4 + j == n) ykeep = fmaf(us[j], Dprm, yc);
      }
    }
    yrow[tw + n] = ykeep;
  }
}

// ---------------- gate + transpose: g=(y*silu(z)) -> gh/gl (n,d) f16 --------
__global__ __launch_bounds__(256) void k_gt(
    const float* __restrict__ y, const float* __restrict__ z,
    _Float16* __restrict__ gh, _Float16* __restrict__ gl) {
  __shared__ _Float16 th[64][68];  // [d_local][t_local]
  __shared__ _Float16 tl[64][68];
  const int ti = threadIdx.x;
  const int t0 = blockIdx.x * 64;
  const int d0 = blockIdx.y * 64;
  const int b = blockIdx.z;
  const int c4 = (ti & 15) * 4;
#pragma unroll
  for (int rr = 0; rr < 4; ++rr) {
    const int dl_ = (ti >> 4) + 16 * rr;
    const size_t base = ((size_t)b * DIM + d0 + dl_) * SEQ + t0 + c4;
    const float4 yv = *(const float4*)(y + base);
    const float4 zv = *(const float4*)(z + base);
    const float gy[4] = {yv.x * silu_f(zv.x), yv.y * silu_f(zv.y),
                         yv.z * silu_f(zv.z), yv.w * silu_f(zv.w)};
#pragma unroll
    for (int k = 0; k < 4; ++k) {
      const _Float16 h = (_Float16)gy[k];
      th[dl_][c4 + k] = h;
      tl[dl_][c4 + k] = (_Float16)(gy[k] - (float)h);
    }
  }
  __syncthreads();
#pragma unroll
  for (int rr = 0; rr < 2; ++rr) {
    const int chunk = ti + 256 * rr;
    const int tloc = chunk >> 3;
    const int dchunk = (chunk & 7) * 8;
    f16x8 hv, lv;
#pragma unroll
    for (int j = 0; j < 8; ++j) {
      hv[j] = th[dchunk + j][tloc];
      lv[j] = tl[dchunk + j][tloc];
    }
    const size_t o = ((size_t)b * SEQ + t0 + tloc) * DIM + d0 + dchunk;
    *(f16x8*)(gh + o) = hv;
    *(f16x8*)(gl + o) = lv;
  }
}

extern "C" void kernel_launch(void* const* d_in, const int* in_sizes, int n_in,
                              void* d_out, int out_size, void* d_ws,
                              size_t ws_size, hipStream_t stream) {
  const float* x          = (const float*)d_in[0];
  const float* in_proj_w  = (const float*)d_in[1];
  const float* conv_w     = (const float*)d_in[2];
  const float* conv_b     = (const float*)d_in[3];
  const float* A_log      = (const float*)d_in[4];
  const float* D_param    = (const float*)d_in[5];
  const float* x_proj_w   = (const float*)d_in[6];
  const float* dt_proj_w  = (const float*)d_in[7];
  const float* dt_proj_b  = (const float*)d_in[8];
  const float* out_proj_w = (const float*)d_in[9];
  float* out = (float*)d_out;
  float* ws = (float*)d_ws;

  const size_t PLANE = (size_t)BATCH * SEQ * DIM;  // 4M floats (16 MB)
  // plane0: xcraw -> delta -> (after pass2) gh/gl f16 planes
  float* xcraw = ws;
  float* delta = ws;
  _Float16* gh = (_Float16*)ws;                    // PLANE f16
  _Float16* gl = (_Float16*)ws + PLANE;            // PLANE f16
  float* xc    = ws + PLANE;      // (b,d,t) post-conv
  float* zbuf  = ws + 2 * PLANE;  // (b,dz,t) channel-major
  // plane3: x hi/lo f16 (dead after kgemm<1>) -> ybuf float
  _Float16* xh = (_Float16*)(ws + 3 * PLANE);
  _Float16* xl = xh + PLANE;
  float* ybuf  = ws + 3 * PLANE;
  float* xdbl  = ws + 4 * PLANE;                    // (b,96,t) 393216 floats
  float* scanP = xdbl + (size_t)BATCH * 96 * SEQ;   // 524288 floats
  float* scanS = scanP + (size_t)LANES * NCH;       // 524288 floats
  _Float16* wih = (_Float16*)(ws + 4 * PLANE + 1572864);
  _Float16* wil = wih + (size_t)2 * DIM * DIM;
  _Float16* woh = wil + (size_t)2 * DIM * DIM;
  _Float16* wol = woh + (size_t)DIM * DIM;

  k_cvt<<<dim3(2048), 256, 0, stream>>>(x, xh, xl, BATCH * SEQ * DIM);
  k_cvt<<<dim3(1024), 256, 0, stream>>>(in_proj_w, wih, wil, 2 * DIM * DIM);
  k_cvt<<<dim3(512), 256, 0, stream>>>(out_proj_w, woh, wol, DIM * DIM);

  kgemm_f16x3<1><<<dim3(32, 16), 256, 0, stream>>>(wih, wil, xh, xl,
                                                   xcraw, zbuf);
  k_conv<<<dim3((BATCH * DIM * SEQ / 4) / 256), 256, 0, stream>>>(
      xcraw, conv_w, conv_b, xc);
  k2_xproj<<<dim3(SEQ / 64, BATCH), 256, 0, stream>>>(xc, x_proj_w, xdbl);
  k3_dtproj<<<dim3(SEQ / 64, DIM / 64, BATCH), 256, 0, stream>>>(
      xdbl, dt_proj_w, dt_proj_b, delta);
  k_scan_pass1<<<dim3(512 * NCH), 64, 0, stream>>>(delta, xc, xdbl, A_log,
                                                   scanP, scanS);
  k_scan_mid<<<dim3(LANES / 64), 64, 0, stream>>>(scanP, scanS);
  k_scan_pass2<<<dim3(512 * NCH), 64, 0, stream>>>(delta, xc, xdbl, A_log,
                                                   D_param, scanS, ybuf);
  k_gt<<<dim3(SEQ / 64, DIM / 64, BATCH), 256, 0, stream>>>(ybuf, zbuf,
                                                            gh, gl);
  kgemm_f16x3<0><<<dim3(8, 32), 256, 0, stream>>>(gh, gl, woh, wol,
                                                  out, nullptr);
}

// Round 5
// 389.308 us; speedup vs baseline: 3.9319x; 1.2205x over previous
//
#include <hip/hip_runtime.h>
#include <math.h>

#define BATCH 2
#define SEQ   2048
#define DIM   1024
#define NST   16
#define DTR   64
#define NCH   16                    // time chunks for the scan
#define CHUNK (SEQ / NCH)           // 128 steps per chunk
#define LANES (BATCH * DIM * NST)   // 32768 scan lanes
#define KSL   8                     // split-K slices for x_proj

typedef _Float16 f16x8 __attribute__((ext_vector_type(8)));
typedef float f32x4 __attribute__((ext_vector_type(4)));

__device__ __forceinline__ float softplus_f(float v) {
  return fmaxf(v, 0.f) + log1pf(expf(-fabsf(v)));
}
__device__ __forceinline__ float silu_f(float v) {
  return v / (1.f + expf(-v));
}

__device__ __forceinline__ void gl_lds16(const _Float16* g, _Float16* l) {
  __builtin_amdgcn_global_load_lds(
      (const __attribute__((address_space(1))) void*)g,
      (__attribute__((address_space(3))) void*)l, 16, 0, 0);
}

#define FMA_ROW(i, av)                                        \
  acc[i][0] = fmaf(av, b.x, acc[i][0]);                       \
  acc[i][1] = fmaf(av, b.y, acc[i][1]);                       \
  acc[i][2] = fmaf(av, b.z, acc[i][2]);                       \
  acc[i][3] = fmaf(av, b.w, acc[i][3]);

// ---------------- split fp32 -> hi/lo f16 planes ----------------
__global__ __launch_bounds__(256) void k_cvt(const float* __restrict__ in,
                                             _Float16* __restrict__ hi,
                                             _Float16* __restrict__ lo,
                                             int n) {
  const int i = (blockIdx.x * 256 + threadIdx.x) * 8;
  if (i >= n) return;
  const float4 a = *(const float4*)(in + i);
  const float4 b = *(const float4*)(in + i + 4);
  const float v[8] = {a.x, a.y, a.z, a.w, b.x, b.y, b.z, b.w};
  f16x8 h, l;
#pragma unroll
  for (int j = 0; j < 8; ++j) {
    const _Float16 hh = (_Float16)v[j];
    h[j] = hh;
    l[j] = (_Float16)(v[j] - (float)hh);
  }
  *(f16x8*)(hi + i) = h;
  *(f16x8*)(lo + i) = l;
}

// ---------------- f16x3 NT GEMM: D[m][n] = sum_k A[m,k]*B[n,k], K=LD=1024 ----
template <int EPI>
__global__ __launch_bounds__(256) void kgemm_f16x3(
    const _Float16* __restrict__ Ah, const _Float16* __restrict__ Al,
    const _Float16* __restrict__ Bh, const _Float16* __restrict__ Bl,
    float* __restrict__ out0, float* __restrict__ out1) {
  __shared__ _Float16 sm[16384];  // 32 KB: Ah|Al|Bh|Bl tiles, 128x32 packed
  _Float16* Ash = sm;
  _Float16* Asl = sm + 4096;
  _Float16* Bsh = sm + 8192;
  _Float16* Bsl = sm + 12288;

  const int tid = threadIdx.x;
  const int wid = tid >> 6, lane = tid & 63;
  const int wm = wid >> 1, wn = wid & 1;
  const int m0 = blockIdx.y * 128;
  const int n0 = blockIdx.x * 128;

  const int r0 = wid * 32;
  const int srow = lane >> 2;
  const int skq = (lane & 3) * 8;
  const _Float16* gAh = Ah + (size_t)(m0 + r0 + srow) * 1024 + skq;
  const _Float16* gAl = Al + (size_t)(m0 + r0 + srow) * 1024 + skq;
  const _Float16* gBh = Bh + (size_t)(n0 + r0 + srow) * 1024 + skq;
  const _Float16* gBl = Bl + (size_t)(n0 + r0 + srow) * 1024 + skq;
  _Float16* lAh = Ash + r0 * 32;
  _Float16* lAl = Asl + r0 * 32;
  _Float16* lBh = Bsh + r0 * 32;
  _Float16* lBl = Bsl + r0 * 32;

  const int fr = lane & 15;
  const int fk = (lane >> 4) * 8;

  f32x4 acc[4][4];
#pragma unroll
  for (int i = 0; i < 4; ++i)
#pragma unroll
    for (int j = 0; j < 4; ++j) acc[i][j] = (f32x4)(0.f);

  for (int k0 = 0; k0 < 1024; k0 += 32) {
    __syncthreads();
    gl_lds16(gAh + k0, lAh);
    gl_lds16(gAh + k0 + 16 * 1024, lAh + 512);
    gl_lds16(gAl + k0, lAl);
    gl_lds16(gAl + k0 + 16 * 1024, lAl + 512);
    gl_lds16(gBh + k0, lBh);
    gl_lds16(gBh + k0 + 16 * 1024, lBh + 512);
    gl_lds16(gBl + k0, lBl);
    gl_lds16(gBl + k0 + 16 * 1024, lBl + 512);
    __syncthreads();

    f16x8 ah[4], alo[4], bh[4], blo[4];
#pragma unroll
    for (int i = 0; i < 4; ++i) {
      const int ao = (wm * 64 + i * 16 + fr) * 32 + fk;
      const int bo = (wn * 64 + i * 16 + fr) * 32 + fk;
      ah[i]  = *(const f16x8*)(Ash + ao);
      alo[i] = *(const f16x8*)(Asl + ao);
      bh[i]  = *(const f16x8*)(Bsh + bo);
      blo[i] = *(const f16x8*)(Bsl + bo);
    }
#pragma unroll
    for (int i = 0; i < 4; ++i)
#pragma unroll
      for (int j = 0; j < 4; ++j) {
        acc[i][j] = __builtin_amdgcn_mfma_f32_16x16x32_f16(ah[i], bh[j],
                                                           acc[i][j], 0, 0, 0);
        acc[i][j] = __builtin_amdgcn_mfma_f32_16x16x32_f16(ah[i], blo[j],
                                                           acc[i][j], 0, 0, 0);
        acc[i][j] = __builtin_amdgcn_mfma_f32_16x16x32_f16(alo[i], bh[j],
                                                           acc[i][j], 0, 0, 0);
      }
  }

  const int lr4 = (lane >> 4) * 4, lc = lane & 15;
#pragma unroll
  for (int i = 0; i < 4; ++i) {
#pragma unroll
    for (int j = 0; j < 4; ++j) {
      const int ar = m0 + wm * 64 + i * 16 + lr4;
      const int bc = n0 + wn * 64 + j * 16 + lc;
#pragma unroll
      for (int r = 0; r < 4; ++r) {
        const float v = acc[i][j][r];
        if (EPI == 0) {
          out0[(size_t)(ar + r) * 1024 + bc] = v;
        } else {
          const int bb = bc >> 11, tt = bc & 2047;
          if (ar < 1024) {
            out0[((size_t)bb * 1024 + ar + r) * 2048 + tt] = v;
          } else {
            out1[((size_t)bb * 1024 + (ar + r - 1024)) * 2048 + tt] = v;
          }
        }
      }
    }
  }
}

// ---------------- conv: depthwise k=3, pad=1, along t ----------------
__global__ __launch_bounds__(256) void k_conv(
    const float* __restrict__ xcraw, const float* __restrict__ cw,
    const float* __restrict__ cb, float* __restrict__ xc) {
  const int idx = blockIdx.x * 256 + threadIdx.x;
  const int t0 = (idx & (SEQ / 4 - 1)) * 4;
  const int r = idx >> 9;  // b*DIM + d
  const int d = r & (DIM - 1);
  const float w0 = cw[d * 3 + 0], w1 = cw[d * 3 + 1], w2 = cw[d * 3 + 2];
  const float bias = cb[d];
  const float* in = xcraw + (size_t)r * SEQ;
  float o[4];
#pragma unroll
  for (int j = 0; j < 4; ++j) {
    const int t = t0 + j;
    const float xm = (t > 0) ? in[t - 1] : 0.f;
    const float x0 = in[t];
    const float xp = (t < SEQ - 1) ? in[t + 1] : 0.f;
    o[j] = fmaf(w0, xm, fmaf(w1, x0, fmaf(w2, xp, bias)));
  }
  *(float4*)(xc + (size_t)r * SEQ + t0) = make_float4(o[0], o[1], o[2], o[3]);
}

// ---------------- K2: x_proj split-K GEMM ----------------
// part[((ks*BATCH + b)*96 + j)*SEQ + t] = sum_{k in slice ks} wp[j,k]*xc[b,k,t]
// grid: (32 t-tiles of 128, KSL k-slices of 128). 256 thr: 6 j x 8 t each.
__global__ __launch_bounds__(256) void k2_xproj_sk(
    const float* __restrict__ xc, const float* __restrict__ wp,
    float* __restrict__ part) {
  __shared__ float As[16][100];   // [kk][j], +4 pad
  __shared__ float Bs[16][132];   // [kk][t], +4 pad
  const int tid = threadIdx.x;
  const int tile = blockIdx.x;            // 0..31
  const int ks = blockIdx.y;              // 0..KSL-1
  const int b = tile >> 4;
  const int t0 = (tile & 15) * 128;
  const int kbase = ks * (DIM / KSL);     // 128-wide K slice
  const int tx = tid & 15, ty = tid >> 4;
  float acc[6][8] = {{0.f}};
  for (int k = 0; k < DIM / KSL; k += 16) {
    // stage A: 96 j x 16 k
    float a_reg[6];
#pragma unroll
    for (int i = 0; i < 6; ++i) {
      const int ii = tid + 256 * i;
      a_reg[i] = wp[(size_t)(ii >> 4) * DIM + kbase + k + (ii & 15)];
    }
    // stage B: 16 k x 128 t
    float4 b_reg[2];
#pragma unroll
    for (int r = 0; r < 2; ++r) {
      const int id2 = tid + 256 * r;
      const int krow = id2 >> 5, t4 = (id2 & 31) * 4;
      b_reg[r] = *(const float4*)(xc + ((size_t)b * DIM + kbase + k + krow) *
                                           SEQ + t0 + t4);
    }
    __syncthreads();
#pragma unroll
    for (int i = 0; i < 6; ++i) {
      const int ii = tid + 256 * i;
      As[ii & 15][ii >> 4] = a_reg[i];
    }
#pragma unroll
    for (int r = 0; r < 2; ++r) {
      const int id2 = tid + 256 * r;
      const int krow = id2 >> 5, t4 = (id2 & 31) * 4;
      *(float4*)&Bs[krow][t4] = b_reg[r];
    }
    __syncthreads();
#pragma unroll
    for (int kk = 0; kk < 16; ++kk) {
      const float4 bA = *(const float4*)&Bs[kk][tx * 4];
      const float4 bB = *(const float4*)&Bs[kk][64 + tx * 4];
#pragma unroll
      for (int i = 0; i < 6; ++i) {
        const float a = As[kk][ty + 16 * i];
        acc[i][0] = fmaf(a, bA.x, acc[i][0]);
        acc[i][1] = fmaf(a, bA.y, acc[i][1]);
        acc[i][2] = fmaf(a, bA.z, acc[i][2]);
        acc[i][3] = fmaf(a, bA.w, acc[i][3]);
        acc[i][4] = fmaf(a, bB.x, acc[i][4]);
        acc[i][5] = fmaf(a, bB.y, acc[i][5]);
        acc[i][6] = fmaf(a, bB.z, acc[i][6]);
        acc[i][7] = fmaf(a, bB.w, acc[i][7]);
      }
    }
    __syncthreads();
  }
#pragma unroll
  for (int i = 0; i < 6; ++i) {
    const int j = ty + 16 * i;
    const size_t o = ((size_t)(ks * BATCH + b) * 96 + j) * SEQ + t0;
    *(float4*)(part + o + tx * 4) =
        make_float4(acc[i][0], acc[i][1], acc[i][2], acc[i][3]);
    *(float4*)(part + o + 64 + tx * 4) =
        make_float4(acc[i][4], acc[i][5], acc[i][6], acc[i][7]);
  }
}

// ---------------- reduce split-K partials -> xdbl ----------------
__global__ __launch_bounds__(256) void k_red(const float* __restrict__ part,
                                             float* __restrict__ xdbl) {
  const size_t PL = (size_t)BATCH * 96 * SEQ;  // 393216
  const size_t i4 = ((size_t)blockIdx.x * 256 + threadIdx.x) * 4;
  float4 s = *(const float4*)(part + i4);
#pragma unroll
  for (int ks = 1; ks < KSL; ++ks) {
    const float4 v = *(const float4*)(part + ks * PL + i4);
    s.x += v.x; s.y += v.y; s.z += v.z; s.w += v.w;
  }
  *(float4*)(xdbl + i4) = s;
}

// ---------------- K3: dt_proj GEMM + softplus (fp32, small) ----------------
__global__ __launch_bounds__(256) void k3_dtproj(
    const float* __restrict__ xdbl, const float* __restrict__ dtw,
    const float* __restrict__ dtb, float* __restrict__ delta) {
  __shared__ float As[16][68];
  __shared__ float Bs[16][68];
  const int tid = threadIdx.x;
  const int b = blockIdx.z;
  const int d0 = blockIdx.y * 64;
  const int t0 = blockIdx.x * 64;
  const int tx = tid & 15, ty = tid >> 4;
  const int lrow = tid >> 2, lcol = (tid & 3) * 4;
  const int bk = tid >> 4, bt4 = (tid & 15) * 4;
  float acc[4][4] = {{0.f}};
  for (int k = 0; k < DTR; k += 16) {
    const float4 av =
        *(const float4*)(dtw + (size_t)(d0 + lrow) * DTR + k + lcol);
    const float4 bv =
        *(const float4*)(xdbl + ((size_t)b * 96 + k + bk) * SEQ + t0 + bt4);
    __syncthreads();
    As[lcol + 0][lrow] = av.x; As[lcol + 1][lrow] = av.y;
    As[lcol + 2][lrow] = av.z; As[lcol + 3][lrow] = av.w;
    Bs[bk][bt4 + 0] = bv.x; Bs[bk][bt4 + 1] = bv.y;
    Bs[bk][bt4 + 2] = bv.z; Bs[bk][bt4 + 3] = bv.w;
    __syncthreads();
#pragma unroll
    for (int kk = 0; kk < 16; ++kk) {
      const float4 a = *(const float4*)&As[kk][ty * 4];
      const float4 b = *(const float4*)&Bs[kk][tx * 4];
      FMA_ROW(0, a.x) FMA_ROW(1, a.y) FMA_ROW(2, a.z) FMA_ROW(3, a.w)
    }
  }
#pragma unroll
  for (int i = 0; i < 4; ++i) {
    const int d = d0 + ty * 4 + i;
    const float bias = dtb[d];
    float4 v;
    v.x = softplus_f(acc[i][0] + bias);
    v.y = softplus_f(acc[i][1] + bias);
    v.z = softplus_f(acc[i][2] + bias);
    v.w = softplus_f(acc[i][3] + bias);
    *(float4*)(delta + ((size_t)b * DIM + d) * SEQ + t0 + tx * 4) = v;
  }
}

// ---------------- scan pass 1: per-chunk product + local end state ----------
__global__ __launch_bounds__(64) void k_scan_pass1(
    const float* __restrict__ delta, const float* __restrict__ u,
    const float* __restrict__ xdbl, const float* __restrict__ A_log,
    float* __restrict__ Pbuf, float* __restrict__ Sbuf) {
  const int lane = threadIdx.x;
  const int grp = lane >> 4, n = lane & 15;
  const int bdblk = blockIdx.x & 511;
  const int chunk = blockIdx.x >> 9;
  const int idx = bdblk * 4 + grp;  // b*DIM + d
  const int b = idx >> 10, d = idx & (DIM - 1);
  const float A = -expf(A_log[d * NST + n]);
  const int tc = chunk * CHUNK;
  const float* drow = delta + (size_t)idx * SEQ + tc;
  const float* urow = u + (size_t)idx * SEQ + tc;
  const float* Brow = xdbl + ((size_t)b * 96 + DTR + n) * SEQ + tc;
  float s = 0.f, dsum = 0.f;
  for (int t0 = 0; t0 < CHUNK; t0 += 4) {
    const float4 dl = *(const float4*)(drow + t0);
    const float4 uu = *(const float4*)(urow + t0);
    const float4 Bv = *(const float4*)(Brow + t0);
    const float dls[4] = {dl.x, dl.y, dl.z, dl.w};
    const float us[4] = {uu.x, uu.y, uu.z, uu.w};
    const float Bb[4] = {Bv.x, Bv.y, Bv.z, Bv.w};
#pragma unroll
    for (int j = 0; j < 4; ++j) {
      dsum += dls[j];
      const float dA = __expf(dls[j] * A);
      s = fmaf(dA, s, dls[j] * us[j] * Bb[j]);
    }
  }
  const int gi = chunk * LANES + bdblk * 64 + lane;
  Pbuf[gi] = __expf(dsum * A);
  Sbuf[gi] = s;
}

// ---------------- scan mid ----------------
__global__ __launch_bounds__(64) void k_scan_mid(
    const float* __restrict__ Pbuf, float* __restrict__ Sbuf) {
  const int gl = blockIdx.x * 64 + threadIdx.x;
  float run = 0.f;
#pragma unroll
  for (int c = 0; c < NCH; ++c) {
    const float p = Pbuf[c * LANES + gl];
    const float s = Sbuf[c * LANES + gl];
    Sbuf[c * LANES + gl] = run;
    run = fmaf(p, run, s);
  }
}

// ---------------- scan pass 2: seeded scan + reduce; y (b,d,t) coalesced ----
__global__ __launch_bounds__(64) void k_scan_pass2(
    const float* __restrict__ delta, const float* __restrict__ u,
    const float* __restrict__ xdbl, const float* __restrict__ A_log,
    const float* __restrict__ Dp, const float* __restrict__ sInit,
    float* __restrict__ y) {
  const int lane = threadIdx.x;
  const int grp = lane >> 4, n = lane & 15;
  const int bdblk = blockIdx.x & 511;
  const int chunk = blockIdx.x >> 9;
  const int idx = bdblk * 4 + grp;  // b*DIM + d
  const int b = idx >> 10, d = idx & (DIM - 1);
  const float A = -expf(A_log[d * NST + n]);
  const float Dprm = Dp[d];
  const int tc = chunk * CHUNK;
  const float* drow = delta + (size_t)idx * SEQ + tc;
  const float* urow = u + (size_t)idx * SEQ + tc;
  const float* Brow = xdbl + ((size_t)b * 96 + DTR + n) * SEQ + tc;
  const float* Crow = xdbl + ((size_t)b * 96 + DTR + NST + n) * SEQ + tc;
  float* yrow = y + (size_t)idx * SEQ + tc;
  float s = sInit[chunk * LANES + bdblk * 64 + lane];
  for (int tw = 0; tw < CHUNK; tw += 16) {
    float ykeep = 0.f;
#pragma unroll
    for (int q = 0; q < 4; ++q) {
      const int t0 = tw + q * 4;
      const float4 dl = *(const float4*)(drow + t0);
      const float4 uu = *(const float4*)(urow + t0);
      const float4 Bv = *(const float4*)(Brow + t0);
      const float4 Cv = *(const float4*)(Crow + t0);
      const float dls[4] = {dl.x, dl.y, dl.z, dl.w};
      const float us[4] = {uu.x, uu.y, uu.z, uu.w};
      const float Bb[4] = {Bv.x, Bv.y, Bv.z, Bv.w};
      const float Cc[4] = {Cv.x, Cv.y, Cv.z, Cv.w};
#pragma unroll
      for (int j = 0; j < 4; ++j) {
        const float dA = __expf(dls[j] * A);
        s = fmaf(dA, s, dls[j] * us[j] * Bb[j]);
        float yc = s * Cc[j];
        yc += __shfl_xor(yc, 1, 64);
        yc += __shfl_xor(yc, 2, 64);
        yc += __shfl_xor(yc, 4, 64);
        yc += __shfl_xor(yc, 8, 64);
        if (q * 4 + j == n) ykeep = fmaf(us[j], Dprm, yc);
      }
    }
    yrow[tw + n] = ykeep;
  }
}

// ---------------- gate + transpose: g=(y*silu(z)) -> gh/gl (n,d) f16 --------
__global__ __launch_bounds__(256) void k_gt(
    const float* __restrict__ y, const float* __restrict__ z,
    _Float16* __restrict__ gh, _Float16* __restrict__ gl) {
  __shared__ _Float16 th[64][68];  // [d_local][t_local]
  __shared__ _Float16 tl[64][68];
  const int ti = threadIdx.x;
  const int t0 = blockIdx.x * 64;
  const int d0 = blockIdx.y * 64;
  const int b = blockIdx.z;
  const int c4 = (ti & 15) * 4;
#pragma unroll
  for (int rr = 0; rr < 4; ++rr) {
    const int dl_ = (ti >> 4) + 16 * rr;
    const size_t base = ((size_t)b * DIM + d0 + dl_) * SEQ + t0 + c4;
    const float4 yv = *(const float4*)(y + base);
    const float4 zv = *(const float4*)(z + base);
    const float gy[4] = {yv.x * silu_f(zv.x), yv.y * silu_f(zv.y),
                         yv.z * silu_f(zv.z), yv.w * silu_f(zv.w)};
#pragma unroll
    for (int k = 0; k < 4; ++k) {
      const _Float16 h = (_Float16)gy[k];
      th[dl_][c4 + k] = h;
      tl[dl_][c4 + k] = (_Float16)(gy[k] - (float)h);
    }
  }
  __syncthreads();
#pragma unroll
  for (int rr = 0; rr < 2; ++rr) {
    const int chunk = ti + 256 * rr;
    const int tloc = chunk >> 3;
    const int dchunk = (chunk & 7) * 8;
    f16x8 hv, lv;
#pragma unroll
    for (int j = 0; j < 8; ++j) {
      hv[j] = th[dchunk + j][tloc];
      lv[j] = tl[dchunk + j][tloc];
    }
    const size_t o = ((size_t)b * SEQ + t0 + tloc) * DIM + d0 + dchunk;
    *(f16x8*)(gh + o) = hv;
    *(f16x8*)(gl + o) = lv;
  }
}

extern "C" void kernel_launch(void* const* d_in, const int* in_sizes, int n_in,
                              void* d_out, int out_size, void* d_ws,
                              size_t ws_size, hipStream_t stream) {
  const float* x          = (const float*)d_in[0];
  const float* in_proj_w  = (const float*)d_in[1];
  const float* conv_w     = (const float*)d_in[2];
  const float* conv_b     = (const float*)d_in[3];
  const float* A_log      = (const float*)d_in[4];
  const float* D_param    = (const float*)d_in[5];
  const float* x_proj_w   = (const float*)d_in[6];
  const float* dt_proj_w  = (const float*)d_in[7];
  const float* dt_proj_b  = (const float*)d_in[8];
  const float* out_proj_w = (const float*)d_in[9];
  float* out = (float*)d_out;
  float* ws = (float*)d_ws;

  const size_t PLANE = (size_t)BATCH * SEQ * DIM;  // 4M floats (16 MB)
  float* xcraw = ws;
  float* delta = ws;
  _Float16* gh = (_Float16*)ws;                    // PLANE f16
  _Float16* gl = (_Float16*)ws + PLANE;            // PLANE f16
  float* xc    = ws + PLANE;      // (b,d,t) post-conv
  float* zbuf  = ws + 2 * PLANE;  // (b,dz,t) channel-major
  // plane3: x hi/lo f16 (dead after kgemm<1>) -> k2 partials -> ybuf
  _Float16* xh = (_Float16*)(ws + 3 * PLANE);
  _Float16* xl = xh + PLANE;
  float* part  = ws + 3 * PLANE;   // KSL * 393216 = 3.1M floats
  float* ybuf  = ws + 3 * PLANE;
  float* xdbl  = ws + 4 * PLANE;                    // (b,96,t) 393216 floats
  float* scanP = xdbl + (size_t)BATCH * 96 * SEQ;   // 524288 floats
  float* scanS = scanP + (size_t)LANES * NCH;       // 524288 floats
  _Float16* wih = (_Float16*)(ws + 4 * PLANE + 1572864);
  _Float16* wil = wih + (size_t)2 * DIM * DIM;
  _Float16* woh = wil + (size_t)2 * DIM * DIM;
  _Float16* wol = woh + (size_t)DIM * DIM;

  k_cvt<<<dim3(2048), 256, 0, stream>>>(x, xh, xl, BATCH * SEQ * DIM);
  k_cvt<<<dim3(1024), 256, 0, stream>>>(in_proj_w, wih, wil, 2 * DIM * DIM);
  k_cvt<<<dim3(512), 256, 0, stream>>>(out_proj_w, woh, wol, DIM * DIM);

  kgemm_f16x3<1><<<dim3(32, 16), 256, 0, stream>>>(wih, wil, xh, xl,
                                                   xcraw, zbuf);
  k_conv<<<dim3((BATCH * DIM * SEQ / 4) / 256), 256, 0, stream>>>(
      xcraw, conv_w, conv_b, xc);
  // k2 partials overwrite xh/xl (dead after kgemm<1>)
  k2_xproj_sk<<<dim3(32, KSL), 256, 0, stream>>>(xc, x_proj_w, part);
  k_red<<<dim3(384), 256, 0, stream>>>(part, xdbl);
  k3_dtproj<<<dim3(SEQ / 64, DIM / 64, BATCH), 256, 0, stream>>>(
      xdbl, dt_proj_w, dt_proj_b, delta);
  k_scan_pass1<<<dim3(512 * NCH), 64, 0, stream>>>(delta, xc, xdbl, A_log,
                                                   scanP, scanS);
  k_scan_mid<<<dim3(LANES / 64), 64, 0, stream>>>(scanP, scanS);
  k_scan_pass2<<<dim3(512 * NCH), 64, 0, stream>>>(delta, xc, xdbl, A_log,
                                                   D_param, scanS, ybuf);
  k_gt<<<dim3(SEQ / 64, DIM / 64, BATCH), 256, 0, stream>>>(ybuf, zbuf,
                                                            gh, gl);
  kgemm_f16x3<0><<<dim3(8, 32), 256, 0, stream>>>(gh, gl, woh, wol,
                                                  out, nullptr);
}